// Round 3
// baseline (1164.174 us; speedup 1.0000x reference)
//
#include <hip/hip_runtime.h>
#include <hip/hip_bf16.h>
#include <stdint.h>

#define N_NODES 8192
#define DD      256
#define KK      512
#define EE      262144
#define BM      32
#define BN      64
#define NDIM    528   // 512 dims + ones-col (dim 512) + pad to 33*16
#define CTS     128

typedef __attribute__((ext_vector_type(8))) short short8;
typedef __attribute__((ext_vector_type(4))) float f32x4;
typedef __attribute__((ext_vector_type(4))) unsigned int u32x4;

static __device__ __forceinline__ short f2bf(float f) {
  unsigned u = __builtin_bit_cast(unsigned, f);
  u = (u + 0x7FFFu + ((u >> 16) & 1u)) >> 16;
  return (short)u;
}
static __device__ __forceinline__ float bf2f(unsigned short s) {
  unsigned u = ((unsigned)s) << 16;
  return __builtin_bit_cast(float, u);
}

// ---------------- workspace layout (bytes) ----------------
static constexpr size_t OFF_CNT  = 0;                          // 8192*4
static constexpr size_t OFF_FLAG = OFF_CNT + 32768;            // 256
static constexpr size_t MEMSET_BYTES = OFF_FLAG + 256;         // 33024
static constexpr size_t OFF_OUTW = 33280;                      // 2 * 8192*512*4 = 33,554,432
static constexpr size_t OFF_L    = OFF_OUTW + 33554432;        // 2 * 8192*4 = 65536
static constexpr size_t OFF_ABF  = OFF_L    + 65536;           // 8192*512*2 = 8,388,608
static constexpr size_t OFF_WT   = OFF_ABF  + 8388608;         // 128*528*64*2 = 8,650,752
static constexpr size_t OFF_BIAS = OFF_WT   + 8650752;         // E*4
static constexpr size_t OFF_RP   = OFF_BIAS + 1048576;         // (8192+1)*4
static constexpr size_t OFF_CUR  = OFF_RP   + 33024;           // 8192*4
static constexpr size_t OFF_MEND = OFF_CUR  + 32768;           // 8192*4
static constexpr size_t OFF_CCOL = OFF_MEND + 32768;           // E*4
static constexpr size_t OFF_CB   = OFF_CCOL + 1048576;         // E*4

// ---------------- prep kernels ----------------

// A = [mag*cos(phase) | mag*sin(phase)]  bf16 [8192][512]
__global__ void k_A(const float* __restrict__ mag, const float* __restrict__ phase,
                    short* __restrict__ Abf) {
  int g = blockIdx.x * 256 + threadIdx.x;       // < 2,097,152
  int i = g >> 8, d = g & 255;
  float mg = mag[g], ph = phase[g];
  float sn, cs;
  sincosf(ph, &sn, &cs);
  Abf[(size_t)i * 512 + d]       = f2bf(mg * cs);
  Abf[(size_t)i * 512 + 256 + d] = f2bf(mg * sn);
}

// Wt_tiled[ct][n][kl] : n<256 -> mag[j][n], n<512 -> phase[j][n-256], n==512 -> 1, else 0 ; j = ct*64+kl
__global__ void k_Wt(const float* __restrict__ mag, const float* __restrict__ phase,
                     short* __restrict__ Wt) {
  int g = blockIdx.x * 256 + threadIdx.x;       // < 4,325,376
  int ct = g / (NDIM * 64);
  int r  = g - ct * (NDIM * 64);
  int n  = r >> 6, kl = r & 63;
  int j  = (ct << 6) + kl;
  float v;
  if (n < 256)      v = mag[j * 256 + n];
  else if (n < 512) v = phase[j * 256 + (n - 256)];
  else              v = (n == 512) ? 1.0f : 0.0f;
  Wt[g] = f2bf(v);
}

// edge MLP: bias = silu(x*w1+b1)@w2 + b2 + dist_scale*x
__global__ void k_bias(const float* __restrict__ ea, const float* __restrict__ w1,
                       const float* __restrict__ b1, const float* __restrict__ w2,
                       const float* __restrict__ b2, const float* __restrict__ ds,
                       float* __restrict__ biasv) {
  int e = blockIdx.x * 256 + threadIdx.x;
  float x = ea[e];
  float acc = 0.f;
#pragma unroll 8
  for (int j = 0; j < 64; ++j) {
    float z = fmaf(x, w1[j], b1[j]);
    float sg = 1.f / (1.f + __expf(-z));
    acc = fmaf(z * sg, w2[j], acc);
  }
  biasv[e] = acc + b2[0] + ds[0] * x;
}

// detect int64 vs int32 edge_index: int64 => all odd 32-bit words (high halves) are 0
__global__ void k_detect(const unsigned* __restrict__ p, int* __restrict__ flag) {
  unsigned acc = 0;
  int idx = blockIdx.x * 256 + threadIdx.x;
  for (int t = idx; t < EE / 2; t += 64 * 256) acc |= p[2 * t + 1];
#pragma unroll
  for (int off = 32; off; off >>= 1) acc |= __shfl_xor(acc, off);
  if ((threadIdx.x & 63) == 0 && acc) atomicOr(flag, 1); // nonzero -> int32 data
}

__device__ __forceinline__ void load_edge(const void* ei, bool is64, int e, int& i, int& j) {
  if (is64) {
    const long long* p = (const long long*)ei;
    i = (int)p[e]; j = (int)p[EE + e];
  } else {
    const int* p = (const int*)ei;
    i = p[e]; j = p[EE + e];
  }
}

__global__ void k_cnt(const void* ei, const int* __restrict__ flag, int* __restrict__ cnt) {
  int e = blockIdx.x * 256 + threadIdx.x;
  bool is64 = (*flag == 0);
  int i, j;
  load_edge(ei, is64, e, i, j);
  atomicAdd(&cnt[i], 1);
}

__global__ void k_scan(const int* __restrict__ cnt, int* __restrict__ row_ptr,
                       int* __restrict__ cursor) {
  __shared__ int part[1024];
  int tid = threadIdx.x;
  int c[8]; int s = 0;
#pragma unroll
  for (int k = 0; k < 8; ++k) { c[k] = cnt[tid * 8 + k]; s += c[k]; }
  part[tid] = s;
  __syncthreads();
  for (int off = 1; off < 1024; off <<= 1) {
    int v = part[tid];
    int add = (tid >= off) ? part[tid - off] : 0;
    __syncthreads();
    part[tid] = v + add;
    __syncthreads();
  }
  int run = part[tid] - s;   // exclusive prefix
#pragma unroll
  for (int k = 0; k < 8; ++k) {
    row_ptr[tid * 8 + k] = run; cursor[tid * 8 + k] = run; run += c[k];
  }
  if (tid == 1023) row_ptr[8192] = run;
}

__global__ void k_scatter(const void* ei, const int* __restrict__ flag,
                          const float* __restrict__ biasv, int* __restrict__ cur,
                          int* __restrict__ ccol, float* __restrict__ cbias) {
  int e = blockIdx.x * 256 + threadIdx.x;
  bool is64 = (*flag == 0);
  int i, j;
  load_edge(ei, is64, e, i, j);
  int pos = atomicAdd(&cur[i], 1);
  ccol[pos] = j;
  cbias[pos] = biasv[e];
}

// per-row: sort edges by col, merge duplicates (sum biases)
__global__ void k_sortmerge(const int* __restrict__ row_ptr, int* __restrict__ col,
                            float* __restrict__ bias, int* __restrict__ mend) {
  int i = blockIdx.x * blockDim.x + threadIdx.x;
  if (i >= N_NODES) return;
  int s = row_ptr[i], e = row_ptr[i + 1];
  for (int a = s + 1; a < e; ++a) {
    int kc = col[a]; float kb = bias[a];
    int b = a - 1;
    while (b >= s && col[b] > kc) { col[b + 1] = col[b]; bias[b + 1] = bias[b]; --b; }
    col[b + 1] = kc; bias[b + 1] = kb;
  }
  int wp = s;
  for (int r2 = s + 1; r2 < e; ++r2) {
    if (col[r2] == col[wp]) bias[wp] += bias[r2];
    else { ++wp; col[wp] = col[r2]; bias[wp] = bias[r2]; }
  }
  mend[i] = (e > s) ? (wp + 1) : s;
}

// ---------------- dense fused attention (no-max softmax) ----------------
// l[i] = sum_j exp(s_ij); outw[i][d] = sum_j exp(s_ij) * W[j][d]
// s accumulated via bf16 MFMA; ones-column of Wt gives l for free (dim 512).
// SPLIT=2 over column tiles; each part writes its own buffer (no atomics).
__global__ __launch_bounds__(256) void k_dense(
    const short* __restrict__ Abf, const short* __restrict__ Wt,
    float* __restrict__ outw, float* __restrict__ l_arr) {
  __shared__ __align__(16) short Ar[BM * KK];   // 32 KB, XOR-swizzled
  __shared__ __align__(16) short Ac[BN * 128];  // 16 KB, XOR-swizzled K-chunk
  __shared__ __align__(16) short Pl[BM * BN];   // 4 KB,  XOR-swizzled

  const int tid  = threadIdx.x;
  const int lane = tid & 63;
  const int w    = tid >> 6;
  const int bid  = blockIdx.x;
  const int sb   = (bid & 7) * 64 + (bid >> 3);  // XCD swizzle over 512 wgs
  const int rb   = sb >> 1;                       // row block 0..255
  const int part = sb & 1;                        // column-tile parity (SPLIT=2)
  const int row0 = rb * BM;

  // stage A_rows[32][512] once (swizzle: LDS chunk x holds global chunk x^(r&7))
#pragma unroll
  for (int m = 0; m < 8; ++m) {
    int cid = m * 256 + tid;
    int r = cid >> 6, x = cid & 63;
    u32x4 v = *(const u32x4*)(Abf + (size_t)(row0 + r) * 512 + ((x ^ (r & 7)) << 3));
    *(u32x4*)(&Ar[(r << 9) + (x << 3)]) = v;
  }

  const int ntlo = (w == 0) ? 0 : (1 + w * 8);   // {0,9,17,25}, counts {9,8,8,8}
  f32x4 zero4 = {0.f, 0.f, 0.f, 0.f};
  f32x4 oacc[2][9];
#pragma unroll
  for (int rt = 0; rt < 2; ++rt)
#pragma unroll
    for (int t = 0; t < 9; ++t) oacc[rt][t] = zero4;

  const int rlow = lane & 15;
  const int kg   = lane >> 4;
  const int col  = (w << 4) + rlow;

#pragma unroll 1
  for (int cti = 0; cti < CTS / 2; ++cti) {
    int ct = cti * 2 + part;
    f32x4 s0 = zero4, s1 = zero4;
#pragma unroll 1
    for (int kc = 0; kc < 4; ++kc) {
      __syncthreads();
      // stage A_cols[64][128] K-chunk kc
#pragma unroll
      for (int m = 0; m < 4; ++m) {
        int cid = m * 256 + tid;
        int r = cid >> 4, x = cid & 15;
        u32x4 v = *(const u32x4*)(Abf + (size_t)(ct * BN + r) * 512 + (kc << 7) + ((x ^ (r & 7)) << 3));
        *(u32x4*)(&Ac[(r << 7) + (x << 3)]) = v;
      }
      __syncthreads();
#pragma unroll
      for (int ks = 0; ks < 4; ++ks) {
        int ch6 = kc * 16 + ks * 4 + kg;
        short8 a0 = *(const short8*)(&Ar[(rlow << 9) + ((ch6 ^ (rlow & 7)) << 3)]);
        short8 a1 = *(const short8*)(&Ar[((rlow + 16) << 9) + ((ch6 ^ (rlow & 7)) << 3)]);
        int ch4 = (ks * 4 + kg) ^ (col & 7);
        short8 b = *(const short8*)(&Ac[(col << 7) + (ch4 << 3)]);
        s0 = __builtin_amdgcn_mfma_f32_16x16x32_bf16(a0, b, s0, 0, 0, 0);
        s1 = __builtin_amdgcn_mfma_f32_16x16x32_bf16(a1, b, s1, 0, 0, 0);
      }
    }
    // exp(scale*s) -> P (bf16, swizzled); C layout: row=(lane>>4)*4+r, col=lane&15
#pragma unroll
    for (int rt = 0; rt < 2; ++rt) {
#pragma unroll
      for (int r = 0; r < 4; ++r) {
        float sv = (rt == 0 ? s0[r] : s1[r]) * 0.0625f;
        float p = __expf(sv);
        int row = (rt << 4) + (kg << 2) + r;
        int cchunk = (col >> 3) ^ (row & 7);
        Pl[(row << 6) + (cchunk << 3) + (col & 7)] = f2bf(p);
      }
    }
    __syncthreads();
    short8 pa00, pa01, pa10, pa11;
    {
      int row = rlow;
      pa00 = *(const short8*)(&Pl[(row << 6) + ((kg ^ (row & 7)) << 3)]);
      pa01 = *(const short8*)(&Pl[(row << 6) + (((kg + 4) ^ (row & 7)) << 3)]);
      row = rlow + 16;
      pa10 = *(const short8*)(&Pl[(row << 6) + ((kg ^ (row & 7)) << 3)]);
      pa11 = *(const short8*)(&Pl[(row << 6) + (((kg + 4) ^ (row & 7)) << 3)]);
    }
    const short* wtb = Wt + (size_t)ct * (NDIM * 64) + (kg << 3);
#pragma unroll
    for (int t = 0; t < 8; ++t) {
      int n = ((ntlo + t) << 4) + rlow;
      const short* wp = wtb + n * 64;
      short8 b0 = *(const short8*)(wp);
      short8 b1 = *(const short8*)(wp + 32);
      oacc[0][t] = __builtin_amdgcn_mfma_f32_16x16x32_bf16(pa00, b0, oacc[0][t], 0, 0, 0);
      oacc[1][t] = __builtin_amdgcn_mfma_f32_16x16x32_bf16(pa10, b0, oacc[1][t], 0, 0, 0);
      oacc[0][t] = __builtin_amdgcn_mfma_f32_16x16x32_bf16(pa01, b1, oacc[0][t], 0, 0, 0);
      oacc[1][t] = __builtin_amdgcn_mfma_f32_16x16x32_bf16(pa11, b1, oacc[1][t], 0, 0, 0);
    }
    if (w == 0) {  // wave 0's 9th tile (tile index 8)
      int n = (8 << 4) + rlow;
      const short* wp = wtb + n * 64;
      short8 b0 = *(const short8*)(wp);
      short8 b1 = *(const short8*)(wp + 32);
      oacc[0][8] = __builtin_amdgcn_mfma_f32_16x16x32_bf16(pa00, b0, oacc[0][8], 0, 0, 0);
      oacc[1][8] = __builtin_amdgcn_mfma_f32_16x16x32_bf16(pa10, b0, oacc[1][8], 0, 0, 0);
      oacc[0][8] = __builtin_amdgcn_mfma_f32_16x16x32_bf16(pa01, b1, oacc[0][8], 0, 0, 0);
      oacc[1][8] = __builtin_amdgcn_mfma_f32_16x16x32_bf16(pa11, b1, oacc[1][8], 0, 0, 0);
    }
  }
  // epilogue: plain stores into this part's buffers
  float* outp = outw + (size_t)part * ((size_t)N_NODES * 512);
  float* lp   = l_arr + part * N_NODES;
#pragma unroll
  for (int rt = 0; rt < 2; ++rt) {
#pragma unroll
    for (int t = 0; t < 9; ++t) {
      if (t == 8 && w != 0) continue;
      int dim = ((ntlo + t) << 4) + rlow;
#pragma unroll
      for (int r = 0; r < 4; ++r) {
        int row = row0 + (rt << 4) + (kg << 2) + r;
        float v = oacc[rt][t][r];
        if (dim < 512)       outp[((size_t)row << 9) + dim] = v;
        else if (dim == 512) lp[row] = v;
      }
    }
  }
}

// ---------------- sparse edge corrections ----------------
// per row i: for each merged edge (j,B): s = dot(A_i,A_j)/16 ;
// l0 += exp(s+B)-exp(s) ; out0[i][:] += (exp(s+B)-exp(s)) * W[j][:]
__global__ __launch_bounds__(256) void k_corr(
    const short* __restrict__ Abf, const float* __restrict__ mag,
    const float* __restrict__ phase,
    const int* __restrict__ row_ptr, const int* __restrict__ mend,
    const int* __restrict__ ccol, const float* __restrict__ cbias,
    float* __restrict__ outw0, float* __restrict__ l0) {
  int i = blockIdx.x;
  int s = row_ptr[i], e = mend[i];
  if (s >= e) return;
  int tid = threadIdx.x, lane = tid & 63, w = tid >> 6;
  __shared__ float red[4];
  __shared__ float wq;
  unsigned av = *(const unsigned*)(Abf + (size_t)i * 512 + tid * 2);
  float a0 = bf2f((unsigned short)(av & 0xFFFF));
  float a1 = bf2f((unsigned short)(av >> 16));
  float acc0 = 0.f, acc1 = 0.f, lacc = 0.f;
  for (int q = s; q < e; ++q) {
    int j = ccol[q]; float B = cbias[q];
    unsigned bv = *(const unsigned*)(Abf + (size_t)j * 512 + tid * 2);
    float p = a0 * bf2f((unsigned short)(bv & 0xFFFF)) + a1 * bf2f((unsigned short)(bv >> 16));
#pragma unroll
    for (int off = 32; off; off >>= 1) p += __shfl_xor(p, off);
    if (lane == 0) red[w] = p;
    __syncthreads();
    if (tid == 0) {
      float st = (red[0] + red[1] + red[2] + red[3]) * 0.0625f;
      wq = __expf(st + B) - __expf(st);
    }
    __syncthreads();
    float wc = wq;
    float2 wv;
    if (tid < 128) wv = *(const float2*)(mag + (size_t)j * 256 + tid * 2);
    else           wv = *(const float2*)(phase + (size_t)j * 256 + (tid * 2 - 256));
    acc0 = fmaf(wc, wv.x, acc0);
    acc1 = fmaf(wc, wv.y, acc1);
    if (tid == 0) lacc += wc;
    __syncthreads();
  }
  outw0[(size_t)i * 512 + tid * 2]     += acc0;
  outw0[(size_t)i * 512 + tid * 2 + 1] += acc1;
  if (tid == 0) l0[i] += lacc;
}

// ---------------- normalize + write f32 output ----------------
__global__ void k_norm(const float* __restrict__ o0, const float* __restrict__ o1,
                       const float* __restrict__ l0, const float* __restrict__ l1,
                       float* __restrict__ out) {
  int g = blockIdx.x * 256 + threadIdx.x;       // < 4,194,304
  int i = g >> 9, d = g & 511;
  float v = (o0[g] + o1[g]) / (l0[i] + l1[i]);
  size_t dst = (d < 256) ? ((size_t)i * 256 + d)
                         : ((size_t)N_NODES * 256 + (size_t)i * 256 + (d - 256));
  out[dst] = v;
}

// ---------------- launch ----------------
extern "C" void kernel_launch(void* const* d_in, const int* in_sizes, int n_in,
                              void* d_out, int out_size, void* d_ws, size_t ws_size,
                              hipStream_t stream) {
  const float* mag   = (const float*)d_in[0];
  const float* phase = (const float*)d_in[1];
  const float* ea    = (const float*)d_in[2];
  const void*  ei    = d_in[3];
  const float* w1    = (const float*)d_in[4];
  const float* b1    = (const float*)d_in[5];
  const float* w2    = (const float*)d_in[6];
  const float* b2    = (const float*)d_in[7];
  const float* ds    = (const float*)d_in[8];

  char* ws = (char*)d_ws;
  int*   cnt   = (int*)(ws + OFF_CNT);
  int*   flag  = (int*)(ws + OFF_FLAG);
  float* outw  = (float*)(ws + OFF_OUTW);   // [2][8192][512]
  float* l_arr = (float*)(ws + OFF_L);      // [2][8192]
  short* Abf   = (short*)(ws + OFF_ABF);
  short* Wt    = (short*)(ws + OFF_WT);
  float* biasv = (float*)(ws + OFF_BIAS);
  int*   rp    = (int*)(ws + OFF_RP);
  int*   cur   = (int*)(ws + OFF_CUR);
  int*   mendp = (int*)(ws + OFF_MEND);
  int*   ccol  = (int*)(ws + OFF_CCOL);
  float* cbias = (float*)(ws + OFF_CB);

  hipMemsetAsync(d_ws, 0, MEMSET_BYTES, stream);
  k_detect<<<64, 256, 0, stream>>>((const unsigned*)ei, flag);
  k_A<<<8192, 256, 0, stream>>>(mag, phase, Abf);
  k_Wt<<<16896, 256, 0, stream>>>(mag, phase, Wt);
  k_bias<<<1024, 256, 0, stream>>>(ea, w1, b1, w2, b2, ds, biasv);
  k_cnt<<<1024, 256, 0, stream>>>(ei, flag, cnt);
  k_scan<<<1, 1024, 0, stream>>>(cnt, rp, cur);
  k_scatter<<<1024, 256, 0, stream>>>(ei, flag, biasv, cur, ccol, cbias);
  k_sortmerge<<<32, 256, 0, stream>>>(rp, ccol, cbias, mendp);
  k_dense<<<512, 256, 0, stream>>>(Abf, Wt, outw, l_arr);
  k_corr<<<8192, 256, 0, stream>>>(Abf, mag, phase, rp, mendp, ccol, cbias, outw, l_arr);
  k_norm<<<16384, 256, 0, stream>>>(outw, outw + (size_t)N_NODES * 512,
                                    l_arr, l_arr + N_NODES, (float*)d_out);
  (void)in_sizes; (void)n_in; (void)out_size; (void)ws_size;
}

// Round 4
// 966.499 us; speedup vs baseline: 1.2045x; 1.2045x over previous
//
#include <hip/hip_runtime.h>
#include <hip/hip_bf16.h>
#include <stdint.h>

#define N_NODES 8192
#define DD      256
#define KK      512
#define EE      262144
#define BM      32
#define BN      64
#define NDIM    528   // 512 dims + ones-col (dim 512) + pad to 33*16
#define CTS     128
#define CORR_CHUNK 512

typedef __attribute__((ext_vector_type(8))) short short8;
typedef __attribute__((ext_vector_type(4))) float f32x4;
typedef __attribute__((ext_vector_type(4))) unsigned int u32x4;

static __device__ __forceinline__ short f2bf(float f) {
  unsigned u = __builtin_bit_cast(unsigned, f);
  u = (u + 0x7FFFu + ((u >> 16) & 1u)) >> 16;
  return (short)u;
}
static __device__ __forceinline__ float bf2f(unsigned short s) {
  unsigned u = ((unsigned)s) << 16;
  return __builtin_bit_cast(float, u);
}

// ---------------- workspace layout (bytes) ----------------
static constexpr size_t OFF_CNT  = 0;                          // 8192*4
static constexpr size_t OFF_FLAG = OFF_CNT + 32768;            // 256
static constexpr size_t MEMSET_BYTES = OFF_FLAG + 256;         // 33024
static constexpr size_t OFF_OUTW = 33280;                      // 2 * 8192*512*4 = 33,554,432
static constexpr size_t OFF_L    = OFF_OUTW + 33554432;        // 2 * 8192*4 = 65536
static constexpr size_t OFF_ABF  = OFF_L    + 65536;           // 8192*512*2 = 8,388,608
static constexpr size_t OFF_WT   = OFF_ABF  + 8388608;         // 128*528*64*2 = 8,650,752
static constexpr size_t OFF_BIAS = OFF_WT   + 8650752;         // E*4
static constexpr size_t OFF_RP   = OFF_BIAS + 1048576;         // (8192+1)*4
static constexpr size_t OFF_CUR  = OFF_RP   + 33024;           // 8192*4
static constexpr size_t OFF_CCOL = OFF_CUR  + 32768;           // E*4
static constexpr size_t OFF_CB   = OFF_CCOL + 1048576;         // E*4

// ---------------- prep kernels ----------------

// A = [mag*cos(phase) | mag*sin(phase)]  bf16 [8192][512]
__global__ void k_A(const float* __restrict__ mag, const float* __restrict__ phase,
                    short* __restrict__ Abf) {
  int g = blockIdx.x * 256 + threadIdx.x;       // < 2,097,152
  int i = g >> 8, d = g & 255;
  float mg = mag[g], ph = phase[g];
  float sn, cs;
  sincosf(ph, &sn, &cs);
  Abf[(size_t)i * 512 + d]       = f2bf(mg * cs);
  Abf[(size_t)i * 512 + 256 + d] = f2bf(mg * sn);
}

// Wt_tiled[ct][n][kl] built via LDS tile-transpose (coalesced both sides).
// grid = 128 ct * 9 ntiles
__global__ void k_Wt(const float* __restrict__ mag, const float* __restrict__ phase,
                     short* __restrict__ Wt) {
  __shared__ short t[64][66];   // pad 66: column read stride 33 dwords -> conflict-free
  int b = blockIdx.x;
  int ct = b / 9, nt = b - ct * 9;
  int n0 = nt * 64;
  int tid = threadIdx.x;
  if (nt < 8) {
    const float* src = (n0 < 256) ? (mag + n0) : (phase + (n0 - 256));
#pragma unroll
    for (int m = 0; m < 16; ++m) {
      int idx = m * 256 + tid;
      int r = idx >> 6, c = idx & 63;
      t[r][c] = f2bf(src[(size_t)(ct * 64 + r) * 256 + c]);
    }
    __syncthreads();
#pragma unroll
    for (int m = 0; m < 16; ++m) {
      int idx = m * 256 + tid;
      int nl = idx >> 6, kl = idx & 63;
      Wt[(size_t)ct * (NDIM * 64) + (size_t)(n0 + nl) * 64 + kl] = t[kl][nl];
    }
  } else {
    // n = 512..527: ones column (512) + zero pad
#pragma unroll
    for (int m = 0; m < 4; ++m) {
      int idx = m * 256 + tid;   // 16 n * 64 kl
      int nl = idx >> 6, kl = idx & 63;
      Wt[(size_t)ct * (NDIM * 64) + (size_t)(512 + nl) * 64 + kl] =
          (nl == 0) ? (short)0x3F80 : (short)0;
    }
  }
}

// edge MLP: bias = silu(x*w1+b1)@w2 + b2 + dist_scale*x
__global__ void k_bias(const float* __restrict__ ea, const float* __restrict__ w1,
                       const float* __restrict__ b1, const float* __restrict__ w2,
                       const float* __restrict__ b2, const float* __restrict__ ds,
                       float* __restrict__ biasv) {
  int e = blockIdx.x * 256 + threadIdx.x;
  float x = ea[e];
  float acc = 0.f;
#pragma unroll 8
  for (int j = 0; j < 64; ++j) {
    float z = fmaf(x, w1[j], b1[j]);
    float sg = 1.f / (1.f + __expf(-z));
    acc = fmaf(z * sg, w2[j], acc);
  }
  biasv[e] = acc + b2[0] + ds[0] * x;
}

// detect int64 vs int32 edge_index: int64 => all odd 32-bit words (high halves) are 0
__global__ void k_detect(const unsigned* __restrict__ p, int* __restrict__ flag) {
  unsigned acc = 0;
  int idx = blockIdx.x * 256 + threadIdx.x;
  for (int t = idx; t < EE / 2; t += 64 * 256) acc |= p[2 * t + 1];
#pragma unroll
  for (int off = 32; off; off >>= 1) acc |= __shfl_xor(acc, off);
  if ((threadIdx.x & 63) == 0 && acc) atomicOr(flag, 1); // nonzero -> int32 data
}

__device__ __forceinline__ void load_edge(const void* ei, bool is64, int e, int& i, int& j) {
  if (is64) {
    const long long* p = (const long long*)ei;
    i = (int)p[e]; j = (int)p[EE + e];
  } else {
    const int* p = (const int*)ei;
    i = p[e]; j = p[EE + e];
  }
}

__global__ void k_cnt(const void* ei, const int* __restrict__ flag, int* __restrict__ cnt) {
  int e = blockIdx.x * 256 + threadIdx.x;
  bool is64 = (*flag == 0);
  int i, j;
  load_edge(ei, is64, e, i, j);
  atomicAdd(&cnt[i], 1);
}

__global__ void k_scan(const int* __restrict__ cnt, int* __restrict__ row_ptr,
                       int* __restrict__ cursor) {
  __shared__ int part[1024];
  int tid = threadIdx.x;
  int c[8]; int s = 0;
#pragma unroll
  for (int k = 0; k < 8; ++k) { c[k] = cnt[tid * 8 + k]; s += c[k]; }
  part[tid] = s;
  __syncthreads();
  for (int off = 1; off < 1024; off <<= 1) {
    int v = part[tid];
    int add = (tid >= off) ? part[tid - off] : 0;
    __syncthreads();
    part[tid] = v + add;
    __syncthreads();
  }
  int run = part[tid] - s;   // exclusive prefix
#pragma unroll
  for (int k = 0; k < 8; ++k) {
    row_ptr[tid * 8 + k] = run; cursor[tid * 8 + k] = run; run += c[k];
  }
  if (tid == 1023) row_ptr[8192] = run;
}

__global__ void k_scatter(const void* ei, const int* __restrict__ flag,
                          const float* __restrict__ biasv, int* __restrict__ cur,
                          int* __restrict__ ccol, float* __restrict__ cbias) {
  int e = blockIdx.x * 256 + threadIdx.x;
  bool is64 = (*flag == 0);
  int i, j;
  load_edge(ei, is64, e, i, j);
  int pos = atomicAdd(&cur[i], 1);
  ccol[pos] = j;
  cbias[pos] = biasv[e];
}

// ---------------- dense fused attention (no-max softmax) ----------------
// l[i] = sum_j exp(s_ij); outw[i][d] = sum_j exp(s_ij) * W[j][d]
// QK^T B-fragments stream directly from global (L2-hot) into registers,
// prefetched one ct ahead; only 2 barriers per ct (Pl exchange).
__global__ __launch_bounds__(256, 2) void k_dense(
    const short* __restrict__ Abf, const short* __restrict__ Wt,
    float* __restrict__ outw, float* __restrict__ l_arr) {
  __shared__ __align__(16) short Ar[BM * KK];   // 32 KB, XOR-swizzled
  __shared__ __align__(16) short Pl[BM * BN];   // 4 KB,  XOR-swizzled

  const int tid  = threadIdx.x;
  const int lane = tid & 63;
  const int w    = tid >> 6;
  const int bid  = blockIdx.x;
  const int sb   = (bid & 7) * 64 + (bid >> 3);  // XCD swizzle over 512 wgs
  const int rb   = sb >> 1;                       // row block 0..255
  const int part = sb & 1;                        // column-tile parity (SPLIT=2)
  const int row0 = rb * BM;

  // stage A_rows[32][512] once (swizzle: LDS chunk x holds global chunk x^(r&7))
#pragma unroll
  for (int m = 0; m < 8; ++m) {
    int cid = m * 256 + tid;
    int r = cid >> 6, x = cid & 63;
    u32x4 v = *(const u32x4*)(Abf + (size_t)(row0 + r) * 512 + ((x ^ (r & 7)) << 3));
    *(u32x4*)(&Ar[(r << 9) + (x << 3)]) = v;
  }

  const int ntlo = (w == 0) ? 0 : (1 + w * 8);   // {0,9,17,25}, counts {9,8,8,8}
  f32x4 zero4 = {0.f, 0.f, 0.f, 0.f};
  f32x4 oacc[2][9];
#pragma unroll
  for (int rt = 0; rt < 2; ++rt)
#pragma unroll
    for (int t = 0; t < 9; ++t) oacc[rt][t] = zero4;

  const int rlow = lane & 15;
  const int kg   = lane >> 4;
  const int col  = (w << 4) + rlow;

  // prefetch first ct's b-frags (global, per-lane contiguous 16B)
  short8 bf[16];
  {
    const short* bp = Abf + ((size_t)(part * 64 + col) << 9) + (kg << 3);
#pragma unroll
    for (int ks2 = 0; ks2 < 16; ++ks2) bf[ks2] = *(const short8*)(bp + ks2 * 32);
  }
  __syncthreads();   // Ar ready

#pragma unroll 1
  for (int cti = 0; cti < CTS / 2; ++cti) {
    const int ct = cti * 2 + part;
    f32x4 s0 = zero4, s1 = zero4;
#pragma unroll
    for (int ks2 = 0; ks2 < 16; ++ks2) {
      int ch6 = (ks2 << 2) + kg;
      short8 a0 = *(const short8*)(&Ar[(rlow << 9) + ((ch6 ^ (rlow & 7)) << 3)]);
      short8 a1 = *(const short8*)(&Ar[((rlow + 16) << 9) + ((ch6 ^ (rlow & 7)) << 3)]);
      s0 = __builtin_amdgcn_mfma_f32_16x16x32_bf16(a0, bf[ks2], s0, 0, 0, 0);
      s1 = __builtin_amdgcn_mfma_f32_16x16x32_bf16(a1, bf[ks2], s1, 0, 0, 0);
    }
    // prefetch next ct's b-frags (reg reuse: lifetimes disjoint; lands during exp+PV)
    {
      const int ctn = (ct + 2 <= CTS - 1) ? (ct + 2) : part;   // harmless wrap on last iter
      const short* bp = Abf + ((size_t)(ctn * 64 + col) << 9) + (kg << 3);
#pragma unroll
      for (int ks2 = 0; ks2 < 16; ++ks2) bf[ks2] = *(const short8*)(bp + ks2 * 32);
    }
    __syncthreads();   // previous iter's Pl reads complete (WAR)
    // exp(scale*s) -> P (bf16, swizzled); C layout: row=(lane>>4)*4+r, col=lane&15
#pragma unroll
    for (int rt = 0; rt < 2; ++rt) {
#pragma unroll
      for (int r = 0; r < 4; ++r) {
        float sv = (rt == 0 ? s0[r] : s1[r]) * 0.0625f;
        float p = __expf(sv);
        int row = (rt << 4) + (kg << 2) + r;
        int cchunk = (col >> 3) ^ (row & 7);
        Pl[(row << 6) + (cchunk << 3) + (col & 7)] = f2bf(p);
      }
    }
    __syncthreads();
    short8 pa00, pa01, pa10, pa11;
    {
      int row = rlow;
      pa00 = *(const short8*)(&Pl[(row << 6) + ((kg ^ (row & 7)) << 3)]);
      pa01 = *(const short8*)(&Pl[(row << 6) + (((kg + 4) ^ (row & 7)) << 3)]);
      row = rlow + 16;
      pa10 = *(const short8*)(&Pl[(row << 6) + ((kg ^ (row & 7)) << 3)]);
      pa11 = *(const short8*)(&Pl[(row << 6) + (((kg + 4) ^ (row & 7)) << 3)]);
    }
    const short* wtb = Wt + (size_t)ct * (NDIM * 64) + (kg << 3);
#pragma unroll
    for (int t = 0; t < 8; ++t) {
      int n = ((ntlo + t) << 4) + rlow;
      const short* wp = wtb + n * 64;
      short8 b0 = *(const short8*)(wp);
      short8 b1 = *(const short8*)(wp + 32);
      oacc[0][t] = __builtin_amdgcn_mfma_f32_16x16x32_bf16(pa00, b0, oacc[0][t], 0, 0, 0);
      oacc[1][t] = __builtin_amdgcn_mfma_f32_16x16x32_bf16(pa10, b0, oacc[1][t], 0, 0, 0);
      oacc[0][t] = __builtin_amdgcn_mfma_f32_16x16x32_bf16(pa01, b1, oacc[0][t], 0, 0, 0);
      oacc[1][t] = __builtin_amdgcn_mfma_f32_16x16x32_bf16(pa11, b1, oacc[1][t], 0, 0, 0);
    }
    if (w == 0) {  // wave 0's 9th tile (tile index 8)
      int n = (8 << 4) + rlow;
      const short* wp = wtb + n * 64;
      short8 b0 = *(const short8*)(wp);
      short8 b1 = *(const short8*)(wp + 32);
      oacc[0][8] = __builtin_amdgcn_mfma_f32_16x16x32_bf16(pa00, b0, oacc[0][8], 0, 0, 0);
      oacc[1][8] = __builtin_amdgcn_mfma_f32_16x16x32_bf16(pa10, b0, oacc[1][8], 0, 0, 0);
      oacc[0][8] = __builtin_amdgcn_mfma_f32_16x16x32_bf16(pa01, b1, oacc[0][8], 0, 0, 0);
      oacc[1][8] = __builtin_amdgcn_mfma_f32_16x16x32_bf16(pa11, b1, oacc[1][8], 0, 0, 0);
    }
  }
  // epilogue: plain stores into this part's buffers
  float* outp = outw + (size_t)part * ((size_t)N_NODES * 512);
  float* lp   = l_arr + part * N_NODES;
#pragma unroll
  for (int rt = 0; rt < 2; ++rt) {
#pragma unroll
    for (int t = 0; t < 9; ++t) {
      if (t == 8 && w != 0) continue;
      int dim = ((ntlo + t) << 4) + rlow;
#pragma unroll
      for (int r = 0; r < 4; ++r) {
        int row = row0 + (rt << 4) + (kg << 2) + r;
        float v = oacc[rt][t][r];
        if (dim < 512)       outp[((size_t)row << 9) + dim] = v;
        else if (dim == 512) lp[row] = v;
      }
    }
  }
}

// ---------------- sparse edge corrections (dedup fused, no sort) ----------------
// per row i, per unique (i,j): delta = exp(s+Bsum)-exp(s); Bsum = sum of dup biases.
// phase A: 4 waves compute edge weights in parallel; phase B: all 256 threads
// accumulate output dims. "first occurrence" scan makes dedup order-independent.
__global__ __launch_bounds__(256) void k_corr(
    const short* __restrict__ Abf, const float* __restrict__ mag,
    const float* __restrict__ phase,
    const int* __restrict__ row_ptr,
    const int* __restrict__ ccol, const float* __restrict__ cbias,
    float* __restrict__ outw0, float* __restrict__ l0) {
  int i = blockIdx.x;
  int s = row_ptr[i], e = row_ptr[i + 1];
  if (s >= e) return;
  int tid = threadIdx.x, lane = tid & 63, w = tid >> 6;
  __shared__ float wq_s[CORR_CHUNK];

  // A_i fragment: lane holds 8 shorts (shared by all waves)
  short8 ai = *(const short8*)(Abf + ((size_t)i << 9) + (lane << 3));
  float aif[8];
#pragma unroll
  for (int u = 0; u < 8; ++u) aif[u] = bf2f((unsigned short)ai[u]);

  float accx = 0.f, accy = 0.f;
  int d = tid * 2;
  const float* wsrc = (d < 256) ? (mag + d) : (phase + (d - 256));

  for (int base = s; base < e; base += CORR_CHUNK) {
    int cl = min(e - base, CORR_CHUNK);
    // phase A: wave w handles edges q = base + w, w+4, ...
    for (int q = base + w; q < base + cl; q += 4) {
      int j = ccol[q];
      short8 aj = *(const short8*)(Abf + ((size_t)j << 9) + (lane << 3));
      float p = 0.f;
#pragma unroll
      for (int u = 0; u < 8; ++u) p = fmaf(aif[u], bf2f((unsigned short)aj[u]), p);
#pragma unroll
      for (int off = 32; off; off >>= 1) p += __shfl_xor(p, off);
      if (lane == 0) {
        float Bsum = 0.f; bool first = true;
        for (int u2 = s; u2 < e; ++u2) {
          if (ccol[u2] == j) { Bsum += cbias[u2]; if (u2 < q) first = false; }
        }
        float st = p * 0.0625f;
        wq_s[q - base] = first ? (__expf(st + Bsum) - __expf(st)) : 0.f;
      }
    }
    __syncthreads();
    // phase B: dims parallel across 256 threads (2 each)
    float lsum = 0.f;
    for (int q2 = 0; q2 < cl; ++q2) {
      float wv = wq_s[q2];
      if (wv != 0.f) {
        int j = ccol[base + q2];
        float2 t2 = *(const float2*)(wsrc + (size_t)j * 256);
        accx = fmaf(wv, t2.x, accx);
        accy = fmaf(wv, t2.y, accy);
        if (tid == 0) lsum += wv;
      }
    }
    if (tid == 0) l0[i] += lsum;
    __syncthreads();   // before next chunk overwrites wq_s
  }
  outw0[((size_t)i << 9) + d]     += accx;
  outw0[((size_t)i << 9) + d + 1] += accy;
}

// ---------------- normalize + write f32 output ----------------
__global__ void k_norm(const float* __restrict__ o0, const float* __restrict__ o1,
                       const float* __restrict__ l0, const float* __restrict__ l1,
                       float* __restrict__ out) {
  int g = blockIdx.x * 256 + threadIdx.x;       // < 4,194,304
  int i = g >> 9, d = g & 511;
  float v = (o0[g] + o1[g]) / (l0[i] + l1[i]);
  size_t dst = (d < 256) ? ((size_t)i * 256 + d)
                         : ((size_t)N_NODES * 256 + (size_t)i * 256 + (d - 256));
  out[dst] = v;
}

// ---------------- launch ----------------
extern "C" void kernel_launch(void* const* d_in, const int* in_sizes, int n_in,
                              void* d_out, int out_size, void* d_ws, size_t ws_size,
                              hipStream_t stream) {
  const float* mag   = (const float*)d_in[0];
  const float* phase = (const float*)d_in[1];
  const float* ea    = (const float*)d_in[2];
  const void*  ei    = d_in[3];
  const float* w1    = (const float*)d_in[4];
  const float* b1    = (const float*)d_in[5];
  const float* w2    = (const float*)d_in[6];
  const float* b2    = (const float*)d_in[7];
  const float* ds    = (const float*)d_in[8];

  char* ws = (char*)d_ws;
  int*   cnt   = (int*)(ws + OFF_CNT);
  int*   flag  = (int*)(ws + OFF_FLAG);
  float* outw  = (float*)(ws + OFF_OUTW);   // [2][8192][512]
  float* l_arr = (float*)(ws + OFF_L);      // [2][8192]
  short* Abf   = (short*)(ws + OFF_ABF);
  short* Wt    = (short*)(ws + OFF_WT);
  float* biasv = (float*)(ws + OFF_BIAS);
  int*   rp    = (int*)(ws + OFF_RP);
  int*   cur   = (int*)(ws + OFF_CUR);
  int*   ccol  = (int*)(ws + OFF_CCOL);
  float* cbias = (float*)(ws + OFF_CB);

  hipMemsetAsync(d_ws, 0, MEMSET_BYTES, stream);
  k_detect<<<64, 256, 0, stream>>>((const unsigned*)ei, flag);
  k_A<<<8192, 256, 0, stream>>>(mag, phase, Abf);
  k_Wt<<<1152, 256, 0, stream>>>(mag, phase, Wt);
  k_bias<<<1024, 256, 0, stream>>>(ea, w1, b1, w2, b2, ds, biasv);
  k_cnt<<<1024, 256, 0, stream>>>(ei, flag, cnt);
  k_scan<<<1, 1024, 0, stream>>>(cnt, rp, cur);
  k_scatter<<<1024, 256, 0, stream>>>(ei, flag, biasv, cur, ccol, cbias);
  k_dense<<<512, 256, 0, stream>>>(Abf, Wt, outw, l_arr);
  k_corr<<<8192, 256, 0, stream>>>(Abf, mag, phase, rp, ccol, cbias, outw, l_arr);
  k_norm<<<16384, 256, 0, stream>>>(outw, outw + (size_t)N_NODES * 512,
                                    l_arr, l_arr + N_NODES, (float*)d_out);
  (void)in_sizes; (void)n_in; (void)out_size; (void)ws_size;
}

// Round 5
// 554.885 us; speedup vs baseline: 2.0980x; 1.7418x over previous
//
#include <hip/hip_runtime.h>
#include <hip/hip_bf16.h>
#include <stdint.h>

#define N_NODES 8192
#define DD      256
#define KK      512
#define EE      262144
#define BMD     128      // rows per block (8 waves x 16)
#define BND     32       // cols per ct step
#define NCT     64       // ct steps per part (SPLIT=4)
#define CORR_CHUNK 512

typedef __attribute__((ext_vector_type(8))) short short8;
typedef __attribute__((ext_vector_type(4))) float f32x4;
typedef __attribute__((ext_vector_type(4))) unsigned int u32x4;

static __device__ __forceinline__ short f2bf(float f) {
  unsigned u = __builtin_bit_cast(unsigned, f);
  u = (u + 0x7FFFu + ((u >> 16) & 1u)) >> 16;
  return (short)u;
}
static __device__ __forceinline__ float bf2f(unsigned short s) {
  unsigned u = ((unsigned)s) << 16;
  return __builtin_bit_cast(float, u);
}

// ---------------- workspace layout (bytes) ----------------
static constexpr size_t OFF_CNT  = 0;                           // 8192*4
static constexpr size_t OFF_FLAG = OFF_CNT + 32768;             // 256
static constexpr size_t OFF_L    = OFF_FLAG + 256;              // 8192*4
static constexpr size_t OFF_OUTW = OFF_L + 32768;               // 8192*512*4 = 16,777,216
static constexpr size_t MEMSET_BYTES = OFF_OUTW + 16777216;     // zero cnt+flag+l+outw
static constexpr size_t OFF_ABF  = MEMSET_BYTES;                // 8192*512*2 = 8,388,608
static constexpr size_t OFF_WT   = OFF_ABF + 8388608;           // 256*512*32*2 = 8,388,608
static constexpr size_t OFF_BIAS = OFF_WT + 8388608;            // E*4
static constexpr size_t OFF_RP   = OFF_BIAS + 1048576;          // (8192+1)*4
static constexpr size_t OFF_CUR  = OFF_RP + 33024;              // 8192*4
static constexpr size_t OFF_CCOL = OFF_CUR + 32768;             // E*4
static constexpr size_t OFF_CB   = OFF_CCOL + 1048576;          // E*4

// ---------------- prep kernels ----------------

// A = [mag*cos(phase) | mag*sin(phase)]  bf16 [8192][512]
__global__ void k_A(const float* __restrict__ mag, const float* __restrict__ phase,
                    short* __restrict__ Abf) {
  int g = blockIdx.x * 256 + threadIdx.x;       // < 2,097,152
  int i = g >> 8, d = g & 255;
  float mg = mag[g], ph = phase[g];
  float sn, cs;
  sincosf(ph, &sn, &cs);
  Abf[(size_t)i * 512 + d]       = f2bf(mg * cs);
  Abf[(size_t)i * 512 + 256 + d] = f2bf(mg * sn);
}

// Wt[ct][n][kl] = W[j=ct*32+kl][n], W = [mag|phase]; built via LDS transpose.
// One block per ct (grid 256).
__global__ void k_Wt(const float* __restrict__ mag, const float* __restrict__ phase,
                     short* __restrict__ Wt) {
  __shared__ short tt[32][520];   // [kl][n], pad 8 for bank spread
  int ct = blockIdx.x, tid = threadIdx.x;
  for (int h = 0; h < 2; ++h) {
    const float* src = h ? phase : mag;
#pragma unroll
    for (int m = 0; m < 32; ++m) {
      int idx = m * 256 + tid;                 // 8192 = 32 kl * 256 c
      int kl = idx >> 8, c = idx & 255;
      tt[kl][h * 256 + c] = f2bf(src[(size_t)(ct * 32 + kl) * 256 + c]);
    }
  }
  __syncthreads();
  short* dst = Wt + ((size_t)ct << 14);        // 512*32 shorts per ct
#pragma unroll
  for (int m = 0; m < 64; ++m) {
    int idx = m * 256 + tid;                   // 16384 = 512 n * 32 kl
    int n = idx >> 5, kl = idx & 31;
    dst[idx] = tt[kl][n];
  }
}

// edge MLP: bias = silu(x*w1+b1)@w2 + b2 + dist_scale*x
__global__ void k_bias(const float* __restrict__ ea, const float* __restrict__ w1,
                       const float* __restrict__ b1, const float* __restrict__ w2,
                       const float* __restrict__ b2, const float* __restrict__ ds,
                       float* __restrict__ biasv) {
  int e = blockIdx.x * 256 + threadIdx.x;
  float x = ea[e];
  float acc = 0.f;
#pragma unroll 8
  for (int j = 0; j < 64; ++j) {
    float z = fmaf(x, w1[j], b1[j]);
    float sg = 1.f / (1.f + __expf(-z));
    acc = fmaf(z * sg, w2[j], acc);
  }
  biasv[e] = acc + b2[0] + ds[0] * x;
}

// detect int64 vs int32 edge_index: int64 => all odd 32-bit words are 0
__global__ void k_detect(const unsigned* __restrict__ p, int* __restrict__ flag) {
  unsigned acc = 0;
  int idx = blockIdx.x * 256 + threadIdx.x;
  for (int t = idx; t < EE / 2; t += 64 * 256) acc |= p[2 * t + 1];
#pragma unroll
  for (int off = 32; off; off >>= 1) acc |= __shfl_xor(acc, off);
  if ((threadIdx.x & 63) == 0 && acc) atomicOr(flag, 1); // nonzero -> int32 data
}

__device__ __forceinline__ void load_edge(const void* ei, bool is64, int e, int& i, int& j) {
  if (is64) {
    const long long* p = (const long long*)ei;
    i = (int)p[e]; j = (int)p[EE + e];
  } else {
    const int* p = (const int*)ei;
    i = p[e]; j = p[EE + e];
  }
}

__global__ void k_cnt(const void* ei, const int* __restrict__ flag, int* __restrict__ cnt) {
  int e = blockIdx.x * 256 + threadIdx.x;
  bool is64 = (*flag == 0);
  int i, j;
  load_edge(ei, is64, e, i, j);
  atomicAdd(&cnt[i], 1);
}

__global__ void k_scan(const int* __restrict__ cnt, int* __restrict__ row_ptr,
                       int* __restrict__ cursor) {
  __shared__ int part[1024];
  int tid = threadIdx.x;
  int c[8]; int s = 0;
#pragma unroll
  for (int k = 0; k < 8; ++k) { c[k] = cnt[tid * 8 + k]; s += c[k]; }
  part[tid] = s;
  __syncthreads();
  for (int off = 1; off < 1024; off <<= 1) {
    int v = part[tid];
    int add = (tid >= off) ? part[tid - off] : 0;
    __syncthreads();
    part[tid] = v + add;
    __syncthreads();
  }
  int run = part[tid] - s;   // exclusive prefix
#pragma unroll
  for (int k = 0; k < 8; ++k) {
    row_ptr[tid * 8 + k] = run; cursor[tid * 8 + k] = run; run += c[k];
  }
  if (tid == 1023) row_ptr[8192] = run;
}

__global__ void k_scatter(const void* ei, const int* __restrict__ flag,
                          const float* __restrict__ biasv, int* __restrict__ cur,
                          int* __restrict__ ccol, float* __restrict__ cbias) {
  int e = blockIdx.x * 256 + threadIdx.x;
  bool is64 = (*flag == 0);
  int i, j;
  load_edge(ei, is64, e, i, j);
  int pos = atomicAdd(&cur[i], 1);
  ccol[pos] = j;
  cbias[pos] = biasv[e];
}

// ---------------- dense fused attention (no-max softmax) ----------------
// 8 waves x 16 rows; A-rows in registers; Ac+Wt double-buffered in LDS via
// global_load_lds; counted vmcnt; raw barriers (2 per ct). SPLIT=4 over cts,
// epilogue atomicAdd into single outw/l.
#define GLD16(g, l) __builtin_amdgcn_global_load_lds( \
    (const __attribute__((address_space(1))) void*)(g), \
    (__attribute__((address_space(3))) void*)(l), 16, 0, 0)

__global__ __launch_bounds__(512, 2) void k_dense(
    const short* __restrict__ Abf, const short* __restrict__ Wt,
    float* __restrict__ outw, float* __restrict__ l_arr) {
  __shared__ __align__(16) short AcB[2][BND * KK];   // 2 x 32 KB, XOR-swizzled chunks
  __shared__ __align__(16) short WtB[2][KK * BND];   // 2 x 32 KB, natural (bank-optimal)
  __shared__ __align__(16) short Pl[8 * 16 * 40];    // per-wave P slice, 80B rows

  const int tid  = threadIdx.x;
  const int lane = tid & 63;
  const int w    = tid >> 6;
  const int rlow = lane & 15;
  const int kg   = lane >> 4;

  const int bid  = blockIdx.x;
  const int sb   = (bid & 7) * 32 + (bid >> 3);   // XCD swizzle over 256 wgs
  const int part = sb >> 6;                        // 0..3 (col quarter)
  const int rb   = sb & 63;                        // 0..63 (row block)
  const int wrow0 = rb * BMD + w * 16;
  const int ct0   = part * NCT;

  // ---- A fragments: this wave's 16 rows x full K, in registers ----
  short8 afr[16];
  {
    const short* ap = Abf + ((size_t)(wrow0 + rlow) << 9) + (kg << 3);
#pragma unroll
    for (int kb = 0; kb < 16; ++kb) afr[kb] = *(const short8*)(ap + (kb << 5));
  }
  asm volatile("s_waitcnt vmcnt(0)" ::: "memory");   // reset vmcnt counting

  // ---- staging: 4 Ac issues + 4 Wt issues per thread (8 total) ----
  // Ac flat slot s: c = s>>6 (row), x = s&63 (chunk); content = global chunk x^(c&7)
#define STAGE(buf, ct) do { \
    const short* acsrc_ = Abf + ((size_t)(ct) << 14); \
    const short* wtsrc_ = Wt + ((size_t)(ct) << 14); \
    _Pragma("unroll") \
    for (int i_ = 0; i_ < 4; ++i_) { \
      int slot_ = i_ * 512 + tid; \
      int c_ = slot_ >> 6, x_ = slot_ & 63; \
      GLD16(acsrc_ + ((size_t)c_ << 9) + ((x_ ^ (c_ & 7)) << 3), \
            (char*)&AcB[buf][0] + i_ * 8192 + w * 1024); \
      GLD16(wtsrc_ + (size_t)slot_ * 8, \
            (char*)&WtB[buf][0] + i_ * 8192 + w * 1024); \
    } \
  } while (0)

  STAGE(0, ct0 + 0);
  STAGE(1, ct0 + 1);

  const f32x4 zero4 = {0.f, 0.f, 0.f, 0.f};
  f32x4 acc[32];
#pragma unroll
  for (int t = 0; t < 32; ++t) acc[t] = zero4;
  float lac[4] = {0.f, 0.f, 0.f, 0.f};
  short* plw = &Pl[w * 640];   // 16 rows x 40 shorts

#pragma unroll 1
  for (int ci = 0; ci < NCT; ++ci) {
    const int cur = ci & 1;
    asm volatile("s_waitcnt vmcnt(8)" ::: "memory");  // current buffer's 8 landed
    __builtin_amdgcn_s_barrier();
    __builtin_amdgcn_sched_barrier(0);

    // ---- QK^T: S[16 rows][32 cols], full K from registers x LDS ----
    const short* ac = &AcB[cur][0];
    f32x4 s0 = zero4, s1 = zero4;
#pragma unroll
    for (int kb = 0; kb < 16; ++kb) {
      int ch = (kb << 2) + kg;
      int sw = (ch ^ (rlow & 7)) << 3;
      short8 b0 = *(const short8*)(ac + (rlow << 9) + sw);
      short8 b1 = *(const short8*)(ac + ((16 + rlow) << 9) + sw);
      s0 = __builtin_amdgcn_mfma_f32_16x16x32_bf16(afr[kb], b0, s0, 0, 0, 0);
      s1 = __builtin_amdgcn_mfma_f32_16x16x32_bf16(afr[kb], b1, s1, 0, 0, 0);
    }

    // ---- exp, l partial, P -> Pl (per-wave, no barrier) ----
    float pr[4];
#pragma unroll
    for (int r = 0; r < 4; ++r) {
      float p0 = __expf(s0[r] * 0.0625f);
      float p1 = __expf(s1[r] * 0.0625f);
      pr[r] = p0 + p1;
      int row = (kg << 2) + r;
      plw[row * 40 + rlow]      = f2bf(p0);
      plw[row * 40 + 16 + rlow] = f2bf(p1);
    }
#pragma unroll
    for (int off = 1; off <= 8; off <<= 1) {
#pragma unroll
      for (int r = 0; r < 4; ++r) pr[r] += __shfl_xor(pr[r], off);
    }
#pragma unroll
    for (int r = 0; r < 4; ++r) lac[r] += pr[r];

    // PV A-fragment: P[row=rlow][k = kg*8..+7]
    short8 pa = *(const short8*)(plw + rlow * 40 + (kg << 3));

    // ---- PV: acc[t] += P(16x32) @ Wt(32x16) over 32 n-tiles ----
    const short* wt = &WtB[cur][0];
#pragma unroll
    for (int t = 0; t < 32; ++t) {
      short8 wb = *(const short8*)(wt + ((t * 16 + rlow) << 5) + (kg << 3));
      acc[t] = __builtin_amdgcn_mfma_f32_16x16x32_bf16(pa, wb, acc[t], 0, 0, 0);
    }

    __builtin_amdgcn_s_barrier();     // all waves done reading buf[cur]
    __builtin_amdgcn_sched_barrier(0);
    STAGE(cur, ct0 + ((ci + 2) & (NCT - 1)));   // wrap at tail (harmless re-stage)
  }

  // ---- epilogue: atomic combine across 4 parts ----
#pragma unroll
  for (int t = 0; t < 32; ++t) {
#pragma unroll
    for (int r = 0; r < 4; ++r) {
      int row = wrow0 + (kg << 2) + r;
      atomicAdd(&outw[((size_t)row << 9) + t * 16 + rlow], acc[t][r]);
    }
  }
  if (rlow == 0) {
#pragma unroll
    for (int r = 0; r < 4; ++r)
      atomicAdd(&l_arr[wrow0 + (kg << 2) + r], lac[r]);
  }
}
#undef STAGE
#undef GLD16

// ---------------- sparse edge corrections (dedup fused, lane-parallel) ----------------
__global__ __launch_bounds__(256) void k_corr(
    const short* __restrict__ Abf, const float* __restrict__ mag,
    const float* __restrict__ phase,
    const int* __restrict__ row_ptr,
    const int* __restrict__ ccol, const float* __restrict__ cbias,
    float* __restrict__ outw, float* __restrict__ l_arr) {
  int i = blockIdx.x;
  int s = row_ptr[i], e = row_ptr[i + 1];
  if (s >= e) return;
  int tid = threadIdx.x, lane = tid & 63, w = tid >> 6;
  __shared__ float wq_s[CORR_CHUNK];

  short8 ai = *(const short8*)(Abf + ((size_t)i << 9) + (lane << 3));
  float aif[8];
#pragma unroll
  for (int u = 0; u < 8; ++u) aif[u] = bf2f((unsigned short)ai[u]);

  float accx = 0.f, accy = 0.f;
  int d = tid * 2;
  const float* wsrc = (d < 256) ? (mag + d) : (phase + (d - 256));

  for (int base = s; base < e; base += CORR_CHUNK) {
    int cl = min(e - base, CORR_CHUNK);
    // phase A: wave w handles edges q = base+w, w+4, ...
    for (int q = base + w; q < base + cl; q += 4) {
      int j = ccol[q];
      short8 aj = *(const short8*)(Abf + ((size_t)j << 9) + (lane << 3));
      float p = 0.f;
#pragma unroll
      for (int u = 0; u < 8; ++u) p = fmaf(aif[u], bf2f((unsigned short)aj[u]), p);
#pragma unroll
      for (int off = 32; off; off >>= 1) p += __shfl_xor(p, off);
      // lane-parallel dup scan: Bsum over all dups, min index
      float bs = 0.f; int mi = 0x7FFFFFFF;
      for (int u2 = s + lane; u2 < e; u2 += 64) {
        if (ccol[u2] == j) { bs += cbias[u2]; mi = min(mi, u2); }
      }
#pragma unroll
      for (int off = 32; off; off >>= 1) {
        bs += __shfl_xor(bs, off);
        mi = min(mi, __shfl_xor(mi, off));
      }
      if (lane == 0) {
        float st = p * 0.0625f;
        wq_s[q - base] = (mi == q) ? (__expf(st + bs) - __expf(st)) : 0.f;
      }
    }
    __syncthreads();
    // phase B: dims parallel across 256 threads (2 each)
    float lsum = 0.f;
    for (int q2 = 0; q2 < cl; ++q2) {
      float wv = wq_s[q2];
      if (wv != 0.f) {
        int j = ccol[base + q2];
        float2 t2 = *(const float2*)(wsrc + (size_t)j * 256);
        accx = fmaf(wv, t2.x, accx);
        accy = fmaf(wv, t2.y, accy);
        if (tid == 0) lsum += wv;
      }
    }
    if (tid == 0) l_arr[i] += lsum;
    __syncthreads();
  }
  outw[((size_t)i << 9) + d]     += accx;
  outw[((size_t)i << 9) + d + 1] += accy;
}

// ---------------- normalize + write f32 output ----------------
__global__ void k_norm(const float* __restrict__ o, const float* __restrict__ l_arr,
                       float* __restrict__ out) {
  int g = blockIdx.x * 256 + threadIdx.x;       // < 4,194,304
  int i = g >> 9, d = g & 511;
  float v = o[g] / l_arr[i];
  size_t dst = (d < 256) ? ((size_t)i * 256 + d)
                         : ((size_t)N_NODES * 256 + (size_t)i * 256 + (d - 256));
  out[dst] = v;
}

// ---------------- launch ----------------
extern "C" void kernel_launch(void* const* d_in, const int* in_sizes, int n_in,
                              void* d_out, int out_size, void* d_ws, size_t ws_size,
                              hipStream_t stream) {
  const float* mag   = (const float*)d_in[0];
  const float* phase = (const float*)d_in[1];
  const float* ea    = (const float*)d_in[2];
  const void*  ei    = d_in[3];
  const float* w1    = (const float*)d_in[4];
  const float* b1    = (const float*)d_in[5];
  const float* w2    = (const float*)d_in[6];
  const float* b2    = (const float*)d_in[7];
  const float* ds    = (const float*)d_in[8];

  char* ws = (char*)d_ws;
  int*   cnt   = (int*)(ws + OFF_CNT);
  int*   flag  = (int*)(ws + OFF_FLAG);
  float* l_arr = (float*)(ws + OFF_L);
  float* outw  = (float*)(ws + OFF_OUTW);
  short* Abf   = (short*)(ws + OFF_ABF);
  short* Wt    = (short*)(ws + OFF_WT);
  float* biasv = (float*)(ws + OFF_BIAS);
  int*   rp    = (int*)(ws + OFF_RP);
  int*   cur   = (int*)(ws + OFF_CUR);
  int*   ccol  = (int*)(ws + OFF_CCOL);
  float* cbias = (float*)(ws + OFF_CB);

  hipMemsetAsync(d_ws, 0, MEMSET_BYTES, stream);
  k_detect<<<64, 256, 0, stream>>>((const unsigned*)ei, flag);
  k_A<<<8192, 256, 0, stream>>>(mag, phase, Abf);
  k_Wt<<<256, 256, 0, stream>>>(mag, phase, Wt);
  k_bias<<<1024, 256, 0, stream>>>(ea, w1, b1, w2, b2, ds, biasv);
  k_cnt<<<1024, 256, 0, stream>>>(ei, flag, cnt);
  k_scan<<<1, 1024, 0, stream>>>(cnt, rp, cur);
  k_scatter<<<1024, 256, 0, stream>>>(ei, flag, biasv, cur, ccol, cbias);
  k_dense<<<256, 512, 0, stream>>>(Abf, Wt, outw, l_arr);
  k_corr<<<8192, 256, 0, stream>>>(Abf, mag, phase, rp, ccol, cbias, outw, l_arr);
  k_norm<<<16384, 256, 0, stream>>>(outw, l_arr, (float*)d_out);
  (void)in_sizes; (void)n_in; (void)out_size; (void)ws_size;
}

// Round 6
// 525.374 us; speedup vs baseline: 2.2159x; 1.0562x over previous
//
#include <hip/hip_runtime.h>
#include <hip/hip_bf16.h>
#include <stdint.h>

#define N_NODES 8192
#define KK      512
#define EE      262144
#define BMD     128      // rows per block (8 waves, 16 rows each for QK)
#define BND     32       // cols per ct step
#define NCT     64       // ct steps per part (SPLIT=4)

typedef __attribute__((ext_vector_type(8))) short short8;
typedef __attribute__((ext_vector_type(4))) float f32x4;
typedef __attribute__((ext_vector_type(4))) unsigned int u32x4;

static __device__ __forceinline__ short f2bf(float f) {
  unsigned u = __builtin_bit_cast(unsigned, f);
  u = (u + 0x7FFFu + ((u >> 16) & 1u)) >> 16;
  return (short)u;
}
static __device__ __forceinline__ float bf2f(unsigned short s) {
  unsigned u = ((unsigned)s) << 16;
  return __builtin_bit_cast(float, u);
}

// ---------------- workspace layout (bytes) ----------------
static constexpr size_t OFF_CNT  = 0;                           // 8192*4
static constexpr size_t OFF_FLAG = OFF_CNT + 32768;             // 256
static constexpr size_t OFF_L    = OFF_FLAG + 256;              // 8192*4
static constexpr size_t OFF_OUTW = OFF_L + 32768;               // 8192*512*4
static constexpr size_t MEMSET_BYTES = OFF_OUTW + 16777216;
static constexpr size_t OFF_ABF  = MEMSET_BYTES;                // 8192*512*2
static constexpr size_t OFF_WT   = OFF_ABF + 8388608;           // 256*16384*2 = 8,388,608
static constexpr size_t OFF_RP   = OFF_WT + 8388608;            // (8192+1)*4
static constexpr size_t OFF_CUR  = OFF_RP + 33024;              // 8192*4
static constexpr size_t OFF_CCOL = OFF_CUR + 32768;             // E*4
static constexpr size_t OFF_CB   = OFF_CCOL + 1048576;          // E*4

// ---------------- prep kernels ----------------

// A = [mag*cos(phase) | mag*sin(phase)]  bf16 [8192][512]
__global__ void k_A(const float* __restrict__ mag, const float* __restrict__ phase,
                    short* __restrict__ Abf) {
  int g = blockIdx.x * 256 + threadIdx.x;       // < 2,097,152
  int i = g >> 8, d = g & 255;
  float mg = mag[g], ph = phase[g];
  float sn, cs;
  sincosf(ph, &sn, &cs);
  Abf[(size_t)i * 512 + d]       = f2bf(mg * cs);
  Abf[(size_t)i * 512 + 256 + d] = f2bf(mg * sn);
}

// Wt[ct][nt(32)][kg(4)][nl(16)][j(8)] = W[ct*32 + kg*8 + j][nt*16 + nl]
// W = [mag|phase] columns. Conflict-free PV B-frag reads in k_dense.
__global__ void k_Wt(const float* __restrict__ mag, const float* __restrict__ phase,
                     short* __restrict__ Wt) {
  __shared__ short tt[32][520];   // [kl][n], padded
  int ct = blockIdx.x, tid = threadIdx.x;
  for (int h = 0; h < 2; ++h) {
    const float* src = h ? phase : mag;
#pragma unroll
    for (int m = 0; m < 32; ++m) {
      int idx = m * 256 + tid;                 // 8192 = 32 kl * 256 c
      int kl = idx >> 8, c = idx & 255;
      tt[kl][h * 256 + c] = f2bf(src[(size_t)(ct * 32 + kl) * 256 + c]);
    }
  }
  __syncthreads();
  short* dst = Wt + ((size_t)ct << 14);        // 16384 shorts per ct
#pragma unroll
  for (int m = 0; m < 64; ++m) {
    int idx = m * 256 + tid;                   // 16384
    int nt = idx >> 9, kgq = (idx >> 7) & 3, nl = (idx >> 3) & 15, j = idx & 7;
    dst[idx] = tt[kgq * 8 + j][nt * 16 + nl];
  }
}

// detect int64 vs int32 edge_index: int64 => all odd 32-bit words are 0
__global__ void k_detect(const unsigned* __restrict__ p, int* __restrict__ flag) {
  unsigned acc = 0;
  int idx = blockIdx.x * 256 + threadIdx.x;
  for (int t = idx; t < EE / 2; t += 256 * 256) acc |= p[2 * t + 1];
#pragma unroll
  for (int off = 32; off; off >>= 1) acc |= __shfl_xor(acc, off);
  if ((threadIdx.x & 63) == 0 && acc) atomicOr(flag, 1); // nonzero -> int32 data
}

__device__ __forceinline__ void load_edge(const void* ei, bool is64, int e, int& i, int& j) {
  if (is64) {
    const long long* p = (const long long*)ei;
    i = (int)p[e]; j = (int)p[EE + e];
  } else {
    const int* p = (const int*)ei;
    i = p[e]; j = p[EE + e];
  }
}

__global__ void k_cnt(const void* ei, const int* __restrict__ flag, int* __restrict__ cnt) {
  int e = blockIdx.x * 256 + threadIdx.x;
  bool is64 = (*flag == 0);
  int i, j;
  load_edge(ei, is64, e, i, j);
  atomicAdd(&cnt[i], 1);
}

__global__ void k_scan(const int* __restrict__ cnt, int* __restrict__ row_ptr,
                       int* __restrict__ cursor) {
  __shared__ int part[1024];
  int tid = threadIdx.x;
  int c[8]; int s = 0;
#pragma unroll
  for (int k = 0; k < 8; ++k) { c[k] = cnt[tid * 8 + k]; s += c[k]; }
  part[tid] = s;
  __syncthreads();
  for (int off = 1; off < 1024; off <<= 1) {
    int v = part[tid];
    int add = (tid >= off) ? part[tid - off] : 0;
    __syncthreads();
    part[tid] = v + add;
    __syncthreads();
  }
  int run = part[tid] - s;   // exclusive prefix
#pragma unroll
  for (int k = 0; k < 8; ++k) {
    row_ptr[tid * 8 + k] = run; cursor[tid * 8 + k] = run; run += c[k];
  }
  if (tid == 1023) row_ptr[8192] = run;
}

// scatter with fused edge-MLP bias
__global__ void k_scatter(const void* ei, const int* __restrict__ flag,
                          const float* __restrict__ ea,
                          const float* __restrict__ w1, const float* __restrict__ b1,
                          const float* __restrict__ w2, const float* __restrict__ b2,
                          const float* __restrict__ ds,
                          int* __restrict__ cur,
                          int* __restrict__ ccol, float* __restrict__ cbias) {
  int e = blockIdx.x * 256 + threadIdx.x;
  bool is64 = (*flag == 0);
  int i, j;
  load_edge(ei, is64, e, i, j);
  float x = ea[e];
  float acc = 0.f;
#pragma unroll 8
  for (int u = 0; u < 64; ++u) {
    float z = fmaf(x, w1[u], b1[u]);
    acc = fmaf(z / (1.f + __expf(-z)), w2[u], acc);
  }
  float bias = acc + b2[0] + ds[0] * x;
  int pos = atomicAdd(&cur[i], 1);
  ccol[pos] = j;
  cbias[pos] = bias;
}

// ---------------- dense fused attention (no-max softmax) ----------------
// 8 waves; QK: wave owns 16 rows (A in regs), reads Ac from LDS.
// P exchanged via shared Pl; PV: wave computes ALL 128 rows x its 64-dim slice
// (4 hoisted Wt frags). 3 raw barriers/ct, counted vmcnt, dbuf global_load_lds.
#define GLD16(g, l) __builtin_amdgcn_global_load_lds( \
    (const __attribute__((address_space(1))) void*)(g), \
    (__attribute__((address_space(3))) void*)(l), 16, 0, 0)

__global__ __launch_bounds__(512, 2) void k_dense(
    const short* __restrict__ Abf, const short* __restrict__ Wt,
    float* __restrict__ outw, float* __restrict__ l_arr) {
  __shared__ __align__(16) short AcB[2][BND * KK];   // 2 x 32 KB, XOR-swizzled chunks
  __shared__ __align__(16) short WtB[2][KK * BND];   // 2 x 32 KB, [nt][kg][nl][j]
  __shared__ __align__(16) short Pl[BMD * 40];       // 128 rows x 40 shorts (80B rows)

  const int tid  = threadIdx.x;
  const int lane = tid & 63;
  const int w    = tid >> 6;
  const int rlow = lane & 15;
  const int kg   = lane >> 4;

  const int bid  = blockIdx.x;
  const int sb   = (bid & 7) * 32 + (bid >> 3);   // XCD swizzle over 256 wgs
  const int part = sb >> 6;                        // 0..3 (col quarter)
  const int rb   = sb & 63;                        // 0..63 (row block)
  const int row0 = rb * BMD;
  const int wrow0 = row0 + w * 16;
  const int ct0   = part * NCT;

  // ---- A fragments: this wave's 16 rows x full K, in registers ----
  short8 afr[16];
  {
    const short* ap = Abf + ((size_t)(wrow0 + rlow) << 9) + (kg << 3);
#pragma unroll
    for (int kb = 0; kb < 16; ++kb) afr[kb] = *(const short8*)(ap + (kb << 5));
  }
  asm volatile("s_waitcnt vmcnt(0)" ::: "memory");   // reset vmcnt counting

  // 8 issues per thread per STAGE (4 Ac + 4 Wt)
#define STAGE(buf, ct) do { \
    const short* acsrc_ = Abf + ((size_t)(ct) << 14); \
    const short* wtsrc_ = Wt + ((size_t)(ct) << 14); \
    _Pragma("unroll") \
    for (int i_ = 0; i_ < 4; ++i_) { \
      int slot_ = i_ * 512 + tid; \
      int c_ = slot_ >> 6, x_ = slot_ & 63; \
      GLD16(acsrc_ + ((size_t)c_ << 9) + ((x_ ^ (c_ & 7)) << 3), \
            (char*)&AcB[buf][0] + i_ * 8192 + w * 1024); \
      GLD16(wtsrc_ + (size_t)slot_ * 8, \
            (char*)&WtB[buf][0] + i_ * 8192 + w * 1024); \
    } \
  } while (0)

  STAGE(0, ct0 + 0);
  STAGE(1, ct0 + 1);

  const f32x4 zero4 = {0.f, 0.f, 0.f, 0.f};
  f32x4 acc[8][4];
#pragma unroll
  for (int rt = 0; rt < 8; ++rt)
#pragma unroll
    for (int dt = 0; dt < 4; ++dt) acc[rt][dt] = zero4;
  float lac[4] = {0.f, 0.f, 0.f, 0.f};

#pragma unroll 1
  for (int ci = 0; ci < NCT; ++ci) {
    const int cur = ci & 1;
    asm volatile("s_waitcnt vmcnt(8)" ::: "memory");  // buf[cur]'s 8 landed
    __builtin_amdgcn_sched_barrier(0);
    __builtin_amdgcn_s_barrier();                      // barrier A
    __builtin_amdgcn_sched_barrier(0);

    // ---- QK^T: S[16 rows][32 cols], K=512 from regs x LDS ----
    const short* ac = &AcB[cur][0];
    f32x4 s0 = zero4, s1 = zero4;
    __builtin_amdgcn_s_setprio(1);
#pragma unroll
    for (int kb = 0; kb < 16; ++kb) {
      int sw = (((kb << 2) + kg) ^ (rlow & 7)) << 3;
      short8 b0 = *(const short8*)(ac + (rlow << 9) + sw);
      short8 b1 = *(const short8*)(ac + ((16 + rlow) << 9) + sw);
      s0 = __builtin_amdgcn_mfma_f32_16x16x32_bf16(afr[kb], b0, s0, 0, 0, 0);
      s1 = __builtin_amdgcn_mfma_f32_16x16x32_bf16(afr[kb], b1, s1, 0, 0, 0);
    }
    __builtin_amdgcn_s_setprio(0);

    // ---- exp, l partial, P -> shared Pl ----
    float pr[4];
#pragma unroll
    for (int r = 0; r < 4; ++r) {
      float p0 = __expf(s0[r] * 0.0625f);
      float p1 = __expf(s1[r] * 0.0625f);
      pr[r] = p0 + p1;
      int prow = (w << 4) + (kg << 2) + r;
      Pl[prow * 40 + rlow]      = f2bf(p0);
      Pl[prow * 40 + 16 + rlow] = f2bf(p1);
    }
#pragma unroll
    for (int off = 1; off <= 8; off <<= 1) {
#pragma unroll
      for (int r = 0; r < 4; ++r) pr[r] += __shfl_xor(pr[r], off);
    }
#pragma unroll
    for (int r = 0; r < 4; ++r) lac[r] += pr[r];

    asm volatile("s_waitcnt lgkmcnt(0)" ::: "memory"); // Pl writes visible
    __builtin_amdgcn_s_barrier();                      // barrier B: Pl ready
    __builtin_amdgcn_sched_barrier(0);

    // ---- PV: all 128 rows x this wave's 64-dim slice ----
    const short* wt = &WtB[cur][0];
    short8 wtf[4];
#pragma unroll
    for (int dt = 0; dt < 4; ++dt)
      wtf[dt] = *(const short8*)(wt + (((w << 2) + dt) << 9) + (kg << 7) + (rlow << 3));
    __builtin_amdgcn_s_setprio(1);
#pragma unroll
    for (int rt = 0; rt < 8; ++rt) {
      short8 pa = *(const short8*)(&Pl[((rt << 4) + rlow) * 40 + (kg << 3)]);
#pragma unroll
      for (int dt = 0; dt < 4; ++dt)
        acc[rt][dt] = __builtin_amdgcn_mfma_f32_16x16x32_bf16(pa, wtf[dt], acc[rt][dt], 0, 0, 0);
    }
    __builtin_amdgcn_s_setprio(0);

    __builtin_amdgcn_s_barrier();                      // barrier C: done reading cur+Pl
    __builtin_amdgcn_sched_barrier(0);
    STAGE(cur, ct0 + ((ci + 2) & (NCT - 1)));          // harmless wrap at tail
  }

  // ---- epilogue: atomic combine across 4 parts ----
#pragma unroll
  for (int rt = 0; rt < 8; ++rt) {
#pragma unroll
    for (int dt = 0; dt < 4; ++dt) {
#pragma unroll
      for (int r = 0; r < 4; ++r) {
        int row = row0 + (rt << 4) + (kg << 2) + r;
        int dim = (w << 6) + (dt << 4) + rlow;
        atomicAdd(&outw[((size_t)row << 9) + dim], acc[rt][dt][r]);
      }
    }
  }
  if (rlow == 0) {
#pragma unroll
    for (int r = 0; r < 4; ++r)
      atomicAdd(&l_arr[wrow0 + (kg << 2) + r], lac[r]);
  }
}
#undef STAGE
#undef GLD16

// ---------------- sparse edge corrections (wave-per-row, no barriers) ----------------
__global__ __launch_bounds__(256) void k_corr(
    const short* __restrict__ Abf, const float* __restrict__ mag,
    const float* __restrict__ phase, const int* __restrict__ row_ptr,
    const int* __restrict__ ccol, const float* __restrict__ cbias,
    float* __restrict__ outw, float* __restrict__ l_arr) {
  int lane = threadIdx.x & 63;
  int i = blockIdx.x * 4 + (threadIdx.x >> 6);
  int s = row_ptr[i], e = row_ptr[i + 1];
  if (s >= e) return;

  short8 ai = *(const short8*)(Abf + ((size_t)i << 9) + (lane << 3));
  float aif[8];
#pragma unroll
  for (int u = 0; u < 8; ++u) aif[u] = bf2f((unsigned short)ai[u]);

  int myq = s + lane;
  bool have = myq < e;
  int jv = have ? ccol[myq] : -1;
  float bv = have ? cbias[myq] : 0.f;

  float acc[8] = {0.f, 0.f, 0.f, 0.f, 0.f, 0.f, 0.f, 0.f};
  float lacc = 0.f;
  int d0 = lane << 3;
  const float* wbase = (d0 < 256) ? (mag + d0) : (phase + (d0 - 256));

  for (int q = s; q < e; ++q) {
    int qs = q - s;
    int j = (qs < 64) ? __shfl(jv, qs) : ccol[q];
    short8 aj = *(const short8*)(Abf + ((size_t)j << 9) + (lane << 3));
    f32x4 w0 = *(const f32x4*)(wbase + ((size_t)j << 8));
    f32x4 w1 = *(const f32x4*)(wbase + ((size_t)j << 8) + 4);
    float p = 0.f;
#pragma unroll
    for (int u = 0; u < 8; ++u) p = fmaf(aif[u], bf2f((unsigned short)aj[u]), p);
    // dup scan: Bsum over all occurrences of j in row, min index
    float bs = (jv == j) ? bv : 0.f;
    int mi = (jv == j) ? myq : 0x7FFFFFFF;
    for (int b2 = s + 64; b2 < e; b2 += 64) {    // rows >64 edges: rare
      int q2 = b2 + lane;
      if (q2 < e && ccol[q2] == j) { bs += cbias[q2]; mi = min(mi, q2); }
    }
#pragma unroll
    for (int off = 32; off; off >>= 1) {
      p  += __shfl_xor(p, off);
      bs += __shfl_xor(bs, off);
      mi  = min(mi, __shfl_xor(mi, off));
    }
    float st = p * 0.0625f;
    float dw = (mi == q) ? (__expf(st + bs) - __expf(st)) : 0.f;
    acc[0] = fmaf(dw, w0[0], acc[0]);
    acc[1] = fmaf(dw, w0[1], acc[1]);
    acc[2] = fmaf(dw, w0[2], acc[2]);
    acc[3] = fmaf(dw, w0[3], acc[3]);
    acc[4] = fmaf(dw, w1[0], acc[4]);
    acc[5] = fmaf(dw, w1[1], acc[5]);
    acc[6] = fmaf(dw, w1[2], acc[6]);
    acc[7] = fmaf(dw, w1[3], acc[7]);
    lacc += dw;
  }
  float* op = outw + ((size_t)i << 9) + d0;
#pragma unroll
  for (int u = 0; u < 8; ++u) op[u] += acc[u];
  if (lane == 0) l_arr[i] += lacc;
}

// ---------------- normalize + write f32 output ----------------
__global__ void k_norm(const float* __restrict__ o, const float* __restrict__ l_arr,
                       float* __restrict__ out) {
  int g = blockIdx.x * 256 + threadIdx.x;       // < 4,194,304
  int i = g >> 9, d = g & 511;
  float v = o[g] / l_arr[i];
  size_t dst = (d < 256) ? ((size_t)i * 256 + d)
                         : ((size_t)N_NODES * 256 + (size_t)i * 256 + (d - 256));
  out[dst] = v;
}

// ---------------- launch ----------------
extern "C" void kernel_launch(void* const* d_in, const int* in_sizes, int n_in,
                              void* d_out, int out_size, void* d_ws, size_t ws_size,
                              hipStream_t stream) {
  const float* mag   = (const float*)d_in[0];
  const float* phase = (const float*)d_in[1];
  const float* ea    = (const float*)d_in[2];
  const void*  ei    = d_in[3];
  const float* w1    = (const float*)d_in[4];
  const float* b1    = (const float*)d_in[5];
  const float* w2    = (const float*)d_in[6];
  const float* b2    = (const float*)d_in[7];
  const float* ds    = (const float*)d_in[8];

  char* ws = (char*)d_ws;
  int*   cnt   = (int*)(ws + OFF_CNT);
  int*   flag  = (int*)(ws + OFF_FLAG);
  float* l_arr = (float*)(ws + OFF_L);
  float* outw  = (float*)(ws + OFF_OUTW);
  short* Abf   = (short*)(ws + OFF_ABF);
  short* Wt    = (short*)(ws + OFF_WT);
  int*   rp    = (int*)(ws + OFF_RP);
  int*   cur   = (int*)(ws + OFF_CUR);
  int*   ccol  = (int*)(ws + OFF_CCOL);
  float* cbias = (float*)(ws + OFF_CB);

  hipMemsetAsync(d_ws, 0, MEMSET_BYTES, stream);
  k_detect<<<256, 256, 0, stream>>>((const unsigned*)ei, flag);
  k_A<<<8192, 256, 0, stream>>>(mag, phase, Abf);
  k_Wt<<<256, 256, 0, stream>>>(mag, phase, Wt);
  k_cnt<<<1024, 256, 0, stream>>>(ei, flag, cnt);
  k_scan<<<1, 1024, 0, stream>>>(cnt, rp, cur);
  k_scatter<<<1024, 256, 0, stream>>>(ei, flag, ea, w1, b1, w2, b2, ds, cur, ccol, cbias);
  k_dense<<<256, 512, 0, stream>>>(Abf, Wt, outw, l_arr);
  k_corr<<<2048, 256, 0, stream>>>(Abf, mag, phase, rp, ccol, cbias, outw, l_arr);
  k_norm<<<16384, 256, 0, stream>>>(outw, l_arr, (float*)d_out);
  (void)in_sizes; (void)n_in; (void)out_size; (void)ws_size;
}

// Round 7
// 470.285 us; speedup vs baseline: 2.4755x; 1.1171x over previous
//
#include <hip/hip_runtime.h>
#include <hip/hip_bf16.h>
#include <stdint.h>

#define N_NODES 8192
#define KK      512
#define EE      262144
#define BMD     128      // rows per block (8 waves, 16 rows each for QK)
#define BND     32       // cols per ct step
#define NCT     64       // ct steps per part (SPLIT=4)

typedef __attribute__((ext_vector_type(8))) short short8;
typedef __attribute__((ext_vector_type(4))) short short4_t;
typedef __attribute__((ext_vector_type(4))) float f32x4;
typedef __attribute__((ext_vector_type(4))) unsigned int u32x4;

static __device__ __forceinline__ short f2bf(float f) {
  unsigned u = __builtin_bit_cast(unsigned, f);
  u = (u + 0x7FFFu + ((u >> 16) & 1u)) >> 16;
  return (short)u;
}
static __device__ __forceinline__ float bf2f(unsigned short s) {
  unsigned u = ((unsigned)s) << 16;
  return __builtin_bit_cast(float, u);
}

// ---------------- workspace layout (bytes) ----------------
static constexpr size_t OFF_CNT  = 0;                           // 8192*4
static constexpr size_t OFF_FLAG = OFF_CNT + 32768;             // 256
static constexpr size_t OFF_L    = OFF_FLAG + 256;              // 8192*4
static constexpr size_t OFF_OUTW = OFF_L + 32768;               // 8192*512*4
static constexpr size_t MEMSET_BYTES = OFF_OUTW + 16777216;
static constexpr size_t OFF_ABF  = MEMSET_BYTES;                // 8192*512*2
static constexpr size_t OFF_WT   = OFF_ABF + 8388608;           // 256*16384*2 = 8,388,608
static constexpr size_t OFF_RP   = OFF_WT + 8388608;            // (8192+1)*4
static constexpr size_t OFF_CUR  = OFF_RP + 33024;              // 8192*4
static constexpr size_t OFF_CCOL = OFF_CUR + 32768;             // E*4
static constexpr size_t OFF_CB   = OFF_CCOL + 1048576;          // E*4

// ---------------- prep kernels ----------------

// A = [mag*cos(phase) | mag*sin(phase)]  bf16 [8192][512]
__global__ void k_A(const float* __restrict__ mag, const float* __restrict__ phase,
                    short* __restrict__ Abf) {
  int g = blockIdx.x * 256 + threadIdx.x;       // < 2,097,152
  int i = g >> 8, d = g & 255;
  float mg = mag[g], ph = phase[g];
  float sn, cs;
  sincosf(ph, &sn, &cs);
  Abf[(size_t)i * 512 + d]       = f2bf(mg * cs);
  Abf[(size_t)i * 512 + 256 + d] = f2bf(mg * sn);
}

// Wt[ct][nt(32)][kg(4)][nl(16)][j(8)] = W[ct*32 + kg*8 + j][nt*16 + nl]
// W = [mag|phase] columns. PV B-frags read as per-wave contiguous 1KB from global.
__global__ void k_Wt(const float* __restrict__ mag, const float* __restrict__ phase,
                     short* __restrict__ Wt) {
  __shared__ short tt[32][520];   // [kl][n], padded
  int ct = blockIdx.x, tid = threadIdx.x;
  for (int h = 0; h < 2; ++h) {
    const float* src = h ? phase : mag;
#pragma unroll
    for (int m = 0; m < 32; ++m) {
      int idx = m * 256 + tid;                 // 8192 = 32 kl * 256 c
      int kl = idx >> 8, c = idx & 255;
      tt[kl][h * 256 + c] = f2bf(src[(size_t)(ct * 32 + kl) * 256 + c]);
    }
  }
  __syncthreads();
  short* dst = Wt + ((size_t)ct << 14);        // 16384 shorts per ct
#pragma unroll
  for (int m = 0; m < 64; ++m) {
    int idx = m * 256 + tid;                   // 16384
    int nt = idx >> 9, kgq = (idx >> 7) & 3, nl = (idx >> 3) & 15, j = idx & 7;
    dst[idx] = tt[kgq * 8 + j][nt * 16 + nl];
  }
}

// detect int64 vs int32 edge_index: int64 => all odd 32-bit words are 0
__global__ void k_detect(const unsigned* __restrict__ p, int* __restrict__ flag) {
  unsigned acc = 0;
  int idx = blockIdx.x * 256 + threadIdx.x;
  for (int t = idx; t < EE / 2; t += 256 * 256) acc |= p[2 * t + 1];
#pragma unroll
  for (int off = 32; off; off >>= 1) acc |= __shfl_xor(acc, off);
  if ((threadIdx.x & 63) == 0 && acc) atomicOr(flag, 1); // nonzero -> int32 data
}

__device__ __forceinline__ void load_edge(const void* ei, bool is64, int e, int& i, int& j) {
  if (is64) {
    const long long* p = (const long long*)ei;
    i = (int)p[e]; j = (int)p[EE + e];
  } else {
    const int* p = (const int*)ei;
    i = p[e]; j = p[EE + e];
  }
}

__global__ void k_cnt(const void* ei, const int* __restrict__ flag, int* __restrict__ cnt) {
  int e = blockIdx.x * 256 + threadIdx.x;
  bool is64 = (*flag == 0);
  int i, j;
  load_edge(ei, is64, e, i, j);
  atomicAdd(&cnt[i], 1);
}

__global__ void k_scan(const int* __restrict__ cnt, int* __restrict__ row_ptr,
                       int* __restrict__ cursor) {
  __shared__ int part[1024];
  int tid = threadIdx.x;
  int c[8]; int s = 0;
#pragma unroll
  for (int k = 0; k < 8; ++k) { c[k] = cnt[tid * 8 + k]; s += c[k]; }
  part[tid] = s;
  __syncthreads();
  for (int off = 1; off < 1024; off <<= 1) {
    int v = part[tid];
    int add = (tid >= off) ? part[tid - off] : 0;
    __syncthreads();
    part[tid] = v + add;
    __syncthreads();
  }
  int run = part[tid] - s;   // exclusive prefix
#pragma unroll
  for (int k = 0; k < 8; ++k) {
    row_ptr[tid * 8 + k] = run; cursor[tid * 8 + k] = run; run += c[k];
  }
  if (tid == 1023) row_ptr[8192] = run;
}

// scatter with fused edge-MLP bias
__global__ void k_scatter(const void* ei, const int* __restrict__ flag,
                          const float* __restrict__ ea,
                          const float* __restrict__ w1, const float* __restrict__ b1,
                          const float* __restrict__ w2, const float* __restrict__ b2,
                          const float* __restrict__ ds,
                          int* __restrict__ cur,
                          int* __restrict__ ccol, float* __restrict__ cbias) {
  int e = blockIdx.x * 256 + threadIdx.x;
  bool is64 = (*flag == 0);
  int i, j;
  load_edge(ei, is64, e, i, j);
  float x = ea[e];
  float acc = 0.f;
#pragma unroll 8
  for (int u = 0; u < 64; ++u) {
    float z = fmaf(x, w1[u], b1[u]);
    acc = fmaf(z / (1.f + __expf(-z)), w2[u], acc);
  }
  float bias = acc + b2[0] + ds[0] * x;
  int pos = atomicAdd(&cur[i], 1);
  ccol[pos] = j;
  cbias[pos] = bias;
}

// ---------------- dense fused attention (no-max softmax) ----------------
// 8 waves; QK: wave owns 16 rows (A in regs), reads Ac from LDS (dbuf via
// global_load_lds, counted vmcnt). PV: Wt frags straight from global (L2-hot,
// issued under QK); P exchanged via Pl (stride-36, 2-way banks). 2 barriers/ct.
#define GLD16(g, l) __builtin_amdgcn_global_load_lds( \
    (const __attribute__((address_space(1))) void*)(g), \
    (__attribute__((address_space(3))) void*)(l), 16, 0, 0)

__global__ __launch_bounds__(512, 2) void k_dense(
    const short* __restrict__ Abf, const short* __restrict__ Wt,
    float* __restrict__ outw, float* __restrict__ l_arr) {
  __shared__ __align__(16) short AcB[2][BND * KK];   // 2 x 32 KB, XOR-swizzled chunks
  __shared__ __align__(16) short Pl[BMD * 36];       // 128 rows x 36 shorts (72B rows)

  const int tid  = threadIdx.x;
  const int lane = tid & 63;
  const int w    = tid >> 6;
  const int rlow = lane & 15;
  const int kg   = lane >> 4;

  const int bid  = blockIdx.x;
  const int sb   = (bid & 7) * 32 + (bid >> 3);   // XCD swizzle over 256 wgs
  const int part = sb >> 6;                        // 0..3 (col quarter)
  const int rb   = sb & 63;                        // 0..63 (row block)
  const int row0 = rb * BMD;
  const int wrow0 = row0 + w * 16;
  const int ct0   = part * NCT;

  // ---- A fragments: this wave's 16 rows x full K, in registers ----
  short8 afr[16];
  {
    const short* ap = Abf + ((size_t)(wrow0 + rlow) << 9) + (kg << 3);
#pragma unroll
    for (int kb = 0; kb < 16; ++kb) afr[kb] = *(const short8*)(ap + (kb << 5));
  }
  asm volatile("s_waitcnt vmcnt(0)" ::: "memory");   // reset vmcnt counting

  // 4 Ac issues per thread per STAGE
#define STAGE(buf, ct) do { \
    const short* acsrc_ = Abf + ((size_t)(ct) << 14); \
    _Pragma("unroll") \
    for (int i_ = 0; i_ < 4; ++i_) { \
      int slot_ = i_ * 512 + tid; \
      int c_ = slot_ >> 6, x_ = slot_ & 63; \
      GLD16(acsrc_ + ((size_t)c_ << 9) + ((x_ ^ (c_ & 7)) << 3), \
            (char*)&AcB[buf][0] + i_ * 8192 + w * 1024); \
    } \
  } while (0)

  STAGE(0, ct0 + 0);
  STAGE(1, ct0 + 1);

  const f32x4 zero4 = {0.f, 0.f, 0.f, 0.f};
  f32x4 acc[8][4];
#pragma unroll
  for (int rt = 0; rt < 8; ++rt)
#pragma unroll
    for (int dt = 0; dt < 4; ++dt) acc[rt][dt] = zero4;
  float lac[4] = {0.f, 0.f, 0.f, 0.f};

#pragma unroll 1
  for (int ci = 0; ci < NCT; ++ci) {
    const int cur = ci & 1;
    const int ct  = ct0 + ci;
    asm volatile("s_waitcnt vmcnt(4)" ::: "memory");  // buf[cur]'s 4 landed
    __builtin_amdgcn_sched_barrier(0);
    __builtin_amdgcn_s_barrier();                      // barrier A
    __builtin_amdgcn_sched_barrier(0);

    // PV Wt frags from global (L2-hot), land during QK
    const short* wtg = Wt + ((size_t)ct << 14) + (((size_t)w << 11)) + (kg << 7) + (rlow << 3);
    short8 wtf0 = *(const short8*)(wtg);
    short8 wtf1 = *(const short8*)(wtg + 512);
    short8 wtf2 = *(const short8*)(wtg + 1024);
    short8 wtf3 = *(const short8*)(wtg + 1536);

    // ---- QK^T: S[16 rows][32 cols], K=512 from regs x LDS ----
    const short* ac = &AcB[cur][0];
    f32x4 s0 = zero4, s1 = zero4;
    __builtin_amdgcn_s_setprio(1);
#pragma unroll
    for (int kb = 0; kb < 16; ++kb) {
      int sw = (((kb << 2) + kg) ^ (rlow & 7)) << 3;
      short8 b0 = *(const short8*)(ac + (rlow << 9) + sw);
      short8 b1 = *(const short8*)(ac + ((16 + rlow) << 9) + sw);
      s0 = __builtin_amdgcn_mfma_f32_16x16x32_bf16(afr[kb], b0, s0, 0, 0, 0);
      s1 = __builtin_amdgcn_mfma_f32_16x16x32_bf16(afr[kb], b1, s1, 0, 0, 0);
    }
    __builtin_amdgcn_s_setprio(0);

    // ---- exp, per-lane l partials, P -> shared Pl ----
#pragma unroll
    for (int r = 0; r < 4; ++r) {
      float p0 = __expf(s0[r] * 0.0625f);
      float p1 = __expf(s1[r] * 0.0625f);
      lac[r] += p0 + p1;
      int prow = (w << 4) + (kg << 2) + r;
      Pl[prow * 36 + rlow]      = f2bf(p0);
      Pl[prow * 36 + 16 + rlow] = f2bf(p1);
    }

    asm volatile("s_waitcnt lgkmcnt(0)" ::: "memory"); // Pl writes visible
    __builtin_amdgcn_s_barrier();                      // barrier B: Pl ready
    __builtin_amdgcn_sched_barrier(0);

    STAGE(cur, ct0 + ((ci + 2) & (NCT - 1)));          // overlaps PV; wrap harmless

    // ---- PV: all 128 rows x this wave's 64-dim slice ----
    __builtin_amdgcn_s_setprio(1);
#pragma unroll
    for (int rt = 0; rt < 8; ++rt) {
      const short* pb = &Pl[((rt << 4) + rlow) * 36 + (kg << 3)];
      short4_t pl0 = *(const short4_t*)(pb);
      short4_t pl1 = *(const short4_t*)(pb + 4);
      short8 pa = {pl0[0], pl0[1], pl0[2], pl0[3], pl1[0], pl1[1], pl1[2], pl1[3]};
      acc[rt][0] = __builtin_amdgcn_mfma_f32_16x16x32_bf16(pa, wtf0, acc[rt][0], 0, 0, 0);
      acc[rt][1] = __builtin_amdgcn_mfma_f32_16x16x32_bf16(pa, wtf1, acc[rt][1], 0, 0, 0);
      acc[rt][2] = __builtin_amdgcn_mfma_f32_16x16x32_bf16(pa, wtf2, acc[rt][2], 0, 0, 0);
      acc[rt][3] = __builtin_amdgcn_mfma_f32_16x16x32_bf16(pa, wtf3, acc[rt][3], 0, 0, 0);
    }
    __builtin_amdgcn_s_setprio(0);
  }

  // ---- epilogue: l butterfly (once) + atomic combine across 4 parts ----
#pragma unroll
  for (int off = 1; off <= 8; off <<= 1) {
#pragma unroll
    for (int r = 0; r < 4; ++r) lac[r] += __shfl_xor(lac[r], off);
  }
  if (rlow == 0) {
#pragma unroll
    for (int r = 0; r < 4; ++r)
      atomicAdd(&l_arr[wrow0 + (kg << 2) + r], lac[r]);
  }
#pragma unroll
  for (int rt = 0; rt < 8; ++rt) {
#pragma unroll
    for (int dt = 0; dt < 4; ++dt) {
#pragma unroll
      for (int r = 0; r < 4; ++r) {
        int row = row0 + (rt << 4) + (kg << 2) + r;
        int dim = (w << 6) + (dt << 4) + rlow;
        atomicAdd(&outw[((size_t)row << 9) + dim], acc[rt][dt][r]);
      }
    }
  }
}
#undef STAGE
#undef GLD16

// ---------------- sparse edge corrections (wave-per-row) ----------------
// fast path (row <= 64 edges): dup-scan once, exps lane-parallel,
// one butterfly per edge. fallback: per-edge scan (rare).
__global__ __launch_bounds__(256) void k_corr(
    const short* __restrict__ Abf, const float* __restrict__ mag,
    const float* __restrict__ phase, const int* __restrict__ row_ptr,
    const int* __restrict__ ccol, const float* __restrict__ cbias,
    float* __restrict__ outw, float* __restrict__ l_arr) {
  int lane = threadIdx.x & 63;
  int i = blockIdx.x * 4 + (threadIdx.x >> 6);
  int s = row_ptr[i], e = row_ptr[i + 1];
  int len = e - s;
  if (len <= 0) return;

  short8 ai = *(const short8*)(Abf + ((size_t)i << 9) + (lane << 3));
  float aif[8];
#pragma unroll
  for (int u = 0; u < 8; ++u) aif[u] = bf2f((unsigned short)ai[u]);

  f32x4 acc0 = {0.f, 0.f, 0.f, 0.f}, acc1 = {0.f, 0.f, 0.f, 0.f};
  float lacc = 0.f;
  int d0 = lane << 3;
  const float* wbase = (d0 < 256) ? (mag + d0) : (phase + (d0 - 256));

  if (len <= 64) {
    int jv = (lane < len) ? ccol[s + lane] : -1;
    float bvv = (lane < len) ? cbias[s + lane] : 0.f;
    // dup scan (once per row): Bsum + first-occurrence index for my edge
    float bs = 0.f; int mi = 64;
    for (int t = 0; t < len; ++t) {
      int c = __shfl(jv, t); float b = __shfl(bvv, t);
      if (c == jv) { bs += b; mi = min(mi, t); }
    }
    // per-edge dots; lane t keeps p_t
    float pown = 0.f;
    for (int t = 0; t < len; ++t) {
      int j = __shfl(jv, t);
      short8 aj = *(const short8*)(Abf + ((size_t)j << 9) + (lane << 3));
      float p = 0.f;
#pragma unroll
      for (int u = 0; u < 8; ++u) p = fmaf(aif[u], bf2f((unsigned short)aj[u]), p);
#pragma unroll
      for (int off = 32; off; off >>= 1) p += __shfl_xor(p, off);
      if (lane == t) pown = p;
    }
    // lane-parallel delta weights
    float dwown = 0.f;
    if (lane < len && mi == lane) {
      float st = pown * 0.0625f;
      dwown = __expf(st + bs) - __expf(st);
    }
    // accumulate over edges
    for (int t = 0; t < len; ++t) {
      float dw = __shfl(dwown, t);
      if (dw != 0.f) {
        int j = __shfl(jv, t);
        f32x4 w0 = *(const f32x4*)(wbase + ((size_t)j << 8));
        f32x4 w1 = *(const f32x4*)(wbase + ((size_t)j << 8) + 4);
#pragma unroll
        for (int u = 0; u < 4; ++u) { acc0[u] = fmaf(dw, w0[u], acc0[u]); acc1[u] = fmaf(dw, w1[u], acc1[u]); }
        lacc += dw;
      }
    }
  } else {
    // fallback: per-edge dup scan (rows with >64 edges are rare)
    int myq = s + lane;
    bool have = myq < e;
    int jv = have ? ccol[myq] : -1;
    float bvv = have ? cbias[myq] : 0.f;
    for (int q = s; q < e; ++q) {
      int qs = q - s;
      int j = (qs < 64) ? __shfl(jv, qs) : ccol[q];
      short8 aj = *(const short8*)(Abf + ((size_t)j << 9) + (lane << 3));
      float p = 0.f;
#pragma unroll
      for (int u = 0; u < 8; ++u) p = fmaf(aif[u], bf2f((unsigned short)aj[u]), p);
      float bs = (jv == j) ? bvv : 0.f;
      int mi = (jv == j) ? myq : 0x7FFFFFFF;
      for (int b2 = s + 64; b2 < e; b2 += 64) {
        int q2 = b2 + lane;
        if (q2 < e && ccol[q2] == j) { bs += cbias[q2]; mi = min(mi, q2); }
      }
#pragma unroll
      for (int off = 32; off; off >>= 1) {
        p  += __shfl_xor(p, off);
        bs += __shfl_xor(bs, off);
        mi  = min(mi, __shfl_xor(mi, off));
      }
      float st = p * 0.0625f;
      float dw = (mi == q) ? (__expf(st + bs) - __expf(st)) : 0.f;
      f32x4 w0 = *(const f32x4*)(wbase + ((size_t)j << 8));
      f32x4 w1 = *(const f32x4*)(wbase + ((size_t)j << 8) + 4);
#pragma unroll
      for (int u = 0; u < 4; ++u) { acc0[u] = fmaf(dw, w0[u], acc0[u]); acc1[u] = fmaf(dw, w1[u], acc1[u]); }
      lacc += dw;
    }
  }
  float* op = outw + ((size_t)i << 9) + d0;
  f32x4 o0 = *(const f32x4*)(op);
  f32x4 o1 = *(const f32x4*)(op + 4);
#pragma unroll
  for (int u = 0; u < 4; ++u) { o0[u] += acc0[u]; o1[u] += acc1[u]; }
  *(f32x4*)(op)     = o0;
  *(f32x4*)(op + 4) = o1;
  if (lane == 0) l_arr[i] += lacc;
}

// ---------------- normalize + write f32 output ----------------
__global__ void k_norm(const float* __restrict__ o, const float* __restrict__ l_arr,
                       float* __restrict__ out) {
  int g = blockIdx.x * 256 + threadIdx.x;       // < 4,194,304
  int i = g >> 9, d = g & 511;
  float v = o[g] / l_arr[i];
  size_t dst = (d < 256) ? ((size_t)i * 256 + d)
                         : ((size_t)N_NODES * 256 + (size_t)i * 256 + (d - 256));
  out[dst] = v;
}

// ---------------- launch ----------------
extern "C" void kernel_launch(void* const* d_in, const int* in_sizes, int n_in,
                              void* d_out, int out_size, void* d_ws, size_t ws_size,
                              hipStream_t stream) {
  const float* mag   = (const float*)d_in[0];
  const float* phase = (const float*)d_in[1];
  const float* ea    = (const float*)d_in[2];
  const void*  ei    = d_in[3];
  const float* w1    = (const float*)d_in[4];
  const float* b1    = (const float*)d_in[5];
  const float* w2    = (const float*)d_in[6];
  const float* b2    = (const float*)d_in[7];
  const float* ds    = (const float*)d_in[8];

  char* ws = (char*)d_ws;
  int*   cnt   = (int*)(ws + OFF_CNT);
  int*   flag  = (int*)(ws + OFF_FLAG);
  float* l_arr = (float*)(ws + OFF_L);
  float* outw  = (float*)(ws + OFF_OUTW);
  short* Abf   = (short*)(ws + OFF_ABF);
  short* Wt    = (short*)(ws + OFF_WT);
  int*   rp    = (int*)(ws + OFF_RP);
  int*   cur   = (int*)(ws + OFF_CUR);
  int*   ccol  = (int*)(ws + OFF_CCOL);
  float* cbias = (float*)(ws + OFF_CB);

  hipMemsetAsync(d_ws, 0, MEMSET_BYTES, stream);
  k_detect<<<256, 256, 0, stream>>>((const unsigned*)ei, flag);
  k_A<<<8192, 256, 0, stream>>>(mag, phase, Abf);
  k_Wt<<<256, 256, 0, stream>>>(mag, phase, Wt);
  k_cnt<<<1024, 256, 0, stream>>>(ei, flag, cnt);
  k_scan<<<1, 1024, 0, stream>>>(cnt, rp, cur);
  k_scatter<<<1024, 256, 0, stream>>>(ei, flag, ea, w1, b1, w2, b2, ds, cur, ccol, cbias);
  k_dense<<<256, 512, 0, stream>>>(Abf, Wt, outw, l_arr);
  k_corr<<<2048, 256, 0, stream>>>(Abf, mag, phase, rp, ccol, cbias, outw, l_arr);
  k_norm<<<16384, 256, 0, stream>>>(outw, l_arr, (float*)d_out);
  (void)in_sizes; (void)n_in; (void)out_size; (void)ws_size;
}